// Round 3
// baseline (225.953 us; speedup 1.0000x reference)
//
#include <hip/hip_runtime.h>
#include <hip/hip_bf16.h>
#include <cstdint>

// B=4, S=2048, E=1024, H=16, D=64, SCALE = 1/8
#define SCALE_F 0.125f

typedef __attribute__((ext_vector_type(8))) short bf16x8;
typedef __attribute__((ext_vector_type(4))) float f32x4;
typedef __attribute__((ext_vector_type(4))) unsigned short u16x4;
typedef __attribute__((ext_vector_type(8))) unsigned short u16x8;

typedef const __attribute__((address_space(1))) void glb_void;
typedef __attribute__((address_space(3))) void lds_void;

static __device__ __forceinline__ unsigned short f2bf(float f) {
  unsigned u = __builtin_bit_cast(unsigned, f);
  u = (u + 0x7fffu + ((u >> 16) & 1u)) >> 16;
  return (unsigned short)u;
}
static __device__ __forceinline__ float bf2f(unsigned short s) {
  unsigned u = ((unsigned)s) << 16;
  return __builtin_bit_cast(float, u);
}

// ---------------- fused x convert: xb (row-major bf16) + xT (transposed bf16) ----------------
// x: [8192][1024] fp32.  xb[r][c] = bf16(x[r][c]).  xT[c][r] = bf16(x[r][c]).
__global__ __launch_bounds__(256) void cvt_x(const float* __restrict__ x,
                                             unsigned short* __restrict__ xb,
                                             unsigned short* __restrict__ xT) {
  __shared__ unsigned short lds[64][72];   // [srcCol][srcRow], XOR-swizzled rows
  const int t = threadIdx.x;
  const int r0 = blockIdx.x * 64, c0 = blockIdx.y * 64;
#pragma unroll
  for (int pass = 0; pass < 4; ++pass) {
    int r = pass * 16 + (t >> 4);
    int c = (t & 15) * 4;
    float4 v = *(const float4*)(x + (size_t)(r0 + r) * 1024 + c0 + c);
    u16x4 o = { f2bf(v.x), f2bf(v.y), f2bf(v.z), f2bf(v.w) };
    *(u16x4*)(xb + (size_t)(r0 + r) * 1024 + c0 + c) = o;
#pragma unroll
    for (int j = 0; j < 4; ++j) {
      int C = c + j;
      lds[C][r ^ ((C & 7) << 3)] = o[j];   // swizzled store (spreads banks)
    }
  }
  __syncthreads();
#pragma unroll
  for (int pass = 0; pass < 2; ++pass) {
    int rr = pass * 32 + (t >> 3);   // source col = xT row
    int cc = (t & 7) * 8;            // source row group
    u16x8 v = *(const u16x8*)&lds[rr][cc ^ ((rr & 7) << 3)];
    *(u16x8*)(xT + (size_t)(c0 + rr) * 8192 + r0 + cc) = v;
  }
}

// ---------------- merged weight converts: wk, wv, wob ----------------
__global__ __launch_bounds__(256) void cvt_w(const float* __restrict__ wqkv,
                                             const float* __restrict__ wo,
                                             unsigned short* __restrict__ wk,
                                             unsigned short* __restrict__ wv,
                                             unsigned short* __restrict__ wob) {
  int row = blockIdx.x;            // 0..3071
  const float* src;
  unsigned short* dst;
  if (row < 1024) {                // K rows
    int h = row >> 6, k = row & 63;
    src = wqkv + (size_t)(h * 192 + 64 + k) * 1024;
    dst = wk + (size_t)row * 1024;
  } else if (row < 2048) {         // V rows
    int local = row - 1024;
    int h = local >> 6, k = local & 63;
    src = wqkv + (size_t)(h * 192 + 128 + k) * 1024;
    dst = wv + (size_t)local * 1024;
  } else {                         // O rows
    int local = row - 2048;
    src = wo + (size_t)local * 1024;
    dst = wob + (size_t)local * 1024;
  }
  float4 v = *(const float4*)(src + threadIdx.x * 4);
  u16x4 o = { f2bf(v.x), f2bf(v.y), f2bf(v.z), f2bf(v.w) };
  *(u16x4*)(dst + threadIdx.x * 4) = o;
}

// transpose+cvt for wqt: out[c0+c][r0+r] = bf16(in[srcRow(r0+r)][c0+c]); srcRow(r)=(r>>6)*blk+(r&63)
__global__ __launch_bounds__(256) void transpose_cvt(const float* __restrict__ in,
                                                     unsigned short* __restrict__ out,
                                                     int ldo, int blk) {
  __shared__ unsigned short lds[64][72];
  const int t = threadIdx.x;
  const int r0 = blockIdx.x * 64, c0 = blockIdx.y * 64;
#pragma unroll
  for (int pass = 0; pass < 4; ++pass) {
    int r = pass * 16 + (t >> 4);
    int c = (t & 15) * 4;
    int gr = r0 + r;
    int srcRow = (gr >> 6) * blk + (gr & 63);
    float4 v = *(const float4*)(in + (size_t)srcRow * 1024 + c0 + c);
    lds[c + 0][r] = f2bf(v.x);
    lds[c + 1][r] = f2bf(v.y);
    lds[c + 2][r] = f2bf(v.z);
    lds[c + 3][r] = f2bf(v.w);
  }
  __syncthreads();
#pragma unroll
  for (int pass = 0; pass < 2; ++pass) {
    int rr = pass * 32 + (t >> 3);
    int cc = (t & 7) * 8;
    *(u16x8*)(out + (size_t)(c0 + rr) * ldo + r0 + cc) = *(const u16x8*)&lds[rr][cc];
  }
}

// ---------------- generic m97-style bt GEMM with batch/split-K ----------------
template<bool F32OUT>
__global__ __launch_bounds__(256) void gemm_bt(const unsigned short* __restrict__ A, int lda,
                                               long aB, long aP,
                                               const unsigned short* __restrict__ Bm, int ldb,
                                               long bB, long bP,
                                               void* __restrict__ Cv, int ldc,
                                               long cB, long cP,
                                               int K, int psplit) {
  __shared__ __align__(16) unsigned short Ash[128 * 32];
  __shared__ __align__(16) unsigned short Bsh[128 * 32];
  const int z = blockIdx.z;
  const int bb = z / psplit, pp = z % psplit;
  A  += (size_t)bb * aB + (size_t)pp * aP;
  Bm += (size_t)bb * bB + (size_t)pp * bP;
  const int t = threadIdx.x;
  const int w = t >> 6, l = t & 63;
  const int lr = l & 15, lk = l >> 4;
  const int m0 = blockIdx.y * 128, n0 = blockIdx.x * 128;
  const int wr = (w >> 1) * 64, wc = (w & 1) * 64;
  f32x4 acc[4][4] = {};

  for (int k0 = 0; k0 < K; k0 += 32) {
#pragma unroll
    for (int i = 0; i < 2; ++i) {
      const int c = i * 256 + t;
      const int row = c >> 2, kc = (c & 3) << 3;
      __builtin_amdgcn_global_load_lds(
          (glb_void*)(A + (size_t)(m0 + row) * lda + k0 + kc),
          (lds_void*)(Ash + i * 2048 + w * 512), 16, 0, 0);
      __builtin_amdgcn_global_load_lds(
          (glb_void*)(Bm + (size_t)(n0 + row) * ldb + k0 + kc),
          (lds_void*)(Bsh + i * 2048 + w * 512), 16, 0, 0);
    }
    __syncthreads();

    bf16x8 af[4], bfv[4];
#pragma unroll
    for (int mi = 0; mi < 4; ++mi)
      af[mi] = *(const bf16x8*)(Ash + (wr + mi * 16 + lr) * 32 + lk * 8);
#pragma unroll
    for (int ni = 0; ni < 4; ++ni)
      bfv[ni] = *(const bf16x8*)(Bsh + (wc + ni * 16 + lr) * 32 + lk * 8);
#pragma unroll
    for (int mi = 0; mi < 4; ++mi)
#pragma unroll
      for (int ni = 0; ni < 4; ++ni)
        acc[mi][ni] = __builtin_amdgcn_mfma_f32_16x16x32_bf16(af[mi], bfv[ni], acc[mi][ni], 0, 0, 0);
    __syncthreads();
  }

#pragma unroll
  for (int mi = 0; mi < 4; ++mi)
#pragma unroll
    for (int ni = 0; ni < 4; ++ni)
#pragma unroll
      for (int r = 0; r < 4; ++r) {
        const size_t row = (size_t)(m0 + wr + mi * 16 + lk * 4 + r);
        const size_t col = (size_t)(n0 + wc + ni * 16 + lr);
        if constexpr (F32OUT)
          ((float*)Cv)[(size_t)bb * cB + (size_t)pp * cP + row * ldc + col] = acc[mi][ni][r];
        else
          ((unsigned short*)Cv)[(size_t)bb * cB + (size_t)pp * cP + row * ldc + col] = f2bf(acc[mi][ni][r]);
      }
}

// ---------------- triangular Gram GEMM: Gp[z] tile(mt,nt), mt>=nt, K=512 ----------------
// Gp[z][m][n] = sum_k xT[m][off+k]*xT[n][off+k], off = b*2048 + p*512, z = b*4+p
__global__ __launch_bounds__(256) void gemm_tri(const unsigned short* __restrict__ xT,
                                                unsigned short* __restrict__ Gp) {
  __shared__ __align__(16) unsigned short Ash[128 * 32];
  __shared__ __align__(16) unsigned short Bsh[128 * 32];
  // map blockIdx.x in [0,36) -> (mt,nt) lower triangle
  int ti = blockIdx.x;
  int mt = 0, accum = 0;
  while (accum + mt + 1 <= ti) { accum += mt + 1; ++mt; }
  int nt = ti - accum;
  const int z = blockIdx.z;
  const int b = z >> 2, p = z & 3;
  const unsigned short* base = xT + (size_t)b * 2048 + (size_t)p * 512;

  const int t = threadIdx.x;
  const int w = t >> 6, l = t & 63;
  const int lr = l & 15, lk = l >> 4;
  const int m0 = mt * 128, n0 = nt * 128;
  const int wr = (w >> 1) * 64, wc = (w & 1) * 64;
  f32x4 acc[4][4] = {};

  for (int k0 = 0; k0 < 512; k0 += 32) {
#pragma unroll
    for (int i = 0; i < 2; ++i) {
      const int c = i * 256 + t;
      const int row = c >> 2, kc = (c & 3) << 3;
      __builtin_amdgcn_global_load_lds(
          (glb_void*)(base + (size_t)(m0 + row) * 8192 + k0 + kc),
          (lds_void*)(Ash + i * 2048 + w * 512), 16, 0, 0);
      __builtin_amdgcn_global_load_lds(
          (glb_void*)(base + (size_t)(n0 + row) * 8192 + k0 + kc),
          (lds_void*)(Bsh + i * 2048 + w * 512), 16, 0, 0);
    }
    __syncthreads();

    bf16x8 af[4], bfv[4];
#pragma unroll
    for (int mi = 0; mi < 4; ++mi)
      af[mi] = *(const bf16x8*)(Ash + (wr + mi * 16 + lr) * 32 + lk * 8);
#pragma unroll
    for (int ni = 0; ni < 4; ++ni)
      bfv[ni] = *(const bf16x8*)(Bsh + (wc + ni * 16 + lr) * 32 + lk * 8);
#pragma unroll
    for (int mi = 0; mi < 4; ++mi)
#pragma unroll
      for (int ni = 0; ni < 4; ++ni)
        acc[mi][ni] = __builtin_amdgcn_mfma_f32_16x16x32_bf16(af[mi], bfv[ni], acc[mi][ni], 0, 0, 0);
    __syncthreads();
  }

  unsigned short* out = Gp + (size_t)z * 1048576;
#pragma unroll
  for (int mi = 0; mi < 4; ++mi)
#pragma unroll
    for (int ni = 0; ni < 4; ++ni)
#pragma unroll
      for (int r = 0; r < 4; ++r)
        out[(size_t)(m0 + wr + mi * 16 + lk * 4 + r) * 1024 + n0 + wc + ni * 16 + lr]
            = f2bf(acc[mi][ni][r]);
}

// ---------------- mirror+reduce: G[b] = sum_p Gp[b,p], both triangles ----------------
__global__ __launch_bounds__(256) void mirror_reduce(const unsigned short* __restrict__ Gp,
                                                     unsigned short* __restrict__ G) {
  int ti = blockIdx.x;
  int mt = 0, accum = 0;
  while (accum + mt + 1 <= ti) { accum += mt + 1; ++mt; }
  int nt = ti - accum;
  const int b = blockIdx.y;
  const int m0 = mt * 128, n0 = nt * 128;
  const unsigned short* base = Gp + (size_t)b * 4 * 1048576;
  unsigned short* Gb = G + (size_t)b * 1048576;
  const int t = threadIdx.x;

  // direct tile (mt,nt)
  for (int idx = t * 8; idx < 16384; idx += 2048) {
    int r = idx >> 7, c = idx & 127;
    float s[8] = {};
#pragma unroll
    for (int p = 0; p < 4; ++p) {
      u16x8 v = *(const u16x8*)(base + (size_t)p * 1048576 + (size_t)(m0 + r) * 1024 + n0 + c);
#pragma unroll
      for (int j = 0; j < 8; ++j) s[j] += bf2f(v[j]);
    }
    u16x8 o;
#pragma unroll
    for (int j = 0; j < 8; ++j) o[j] = f2bf(s[j]);
    *(u16x8*)(Gb + (size_t)(m0 + r) * 1024 + n0 + c) = o;
  }

  // mirrored tile (nt,mt): G[n0+r][m0+c+j] = sum_p Gp[p][m0+c+j][n0+r]
  if (mt != nt) {
    for (int idx = t * 8; idx < 16384; idx += 2048) {
      int r = idx >> 7, c = idx & 127;
      float s[8] = {};
#pragma unroll
      for (int j = 0; j < 8; ++j)
#pragma unroll
        for (int p = 0; p < 4; ++p)
          s[j] += bf2f(base[(size_t)p * 1048576 + (size_t)(m0 + c + j) * 1024 + n0 + r]);
      u16x8 o;
#pragma unroll
      for (int j = 0; j < 8; ++j) o[j] = f2bf(s[j]);
      *(u16x8*)(Gb + (size_t)(n0 + r) * 1024 + m0 + c) = o;
    }
  }
}

// ---------------- Mt[b,h][d'][k] = bf16( SCALE * sum_e T1_b[h*64+k][e] * wv[h*64+d'][e] ) ----
// T1p has 2 K-split partials: T1 = T1p[b][0] + T1p[b][1]; fold the sum into the e-loop.
__global__ __launch_bounds__(512) void make_mt(const unsigned short* __restrict__ T1p,
                                               const unsigned short* __restrict__ wv,
                                               unsigned short* __restrict__ Mt) {
  __shared__ float Msh[64][64];
  const int t = threadIdx.x;
  const int w = t >> 6, l = t & 63;       // 8 waves: w = p*4 + ew
  const int lr = l & 15, lk = l >> 4;
  const int bh = blockIdx.x;
  const int b = bh >> 4, h = bh & 15;
  const int p = w >> 2, ew = w & 3;

  for (int i = t; i < 64 * 64; i += 512) ((float*)Msh)[i] = 0.f;
  __syncthreads();

  const unsigned short* Ab = T1p + (size_t)(b * 2 + p) * 1048576 + (size_t)(h * 64) * 1024;
  const unsigned short* Bb = wv + (size_t)(h * 64) * 1024;
  f32x4 acc[4][4] = {};
  const int ebeg = ew * 256;
  for (int e0 = ebeg; e0 < ebeg + 256; e0 += 32) {
    bf16x8 af[4], bfv[4];
#pragma unroll
    for (int mi = 0; mi < 4; ++mi)
      af[mi] = *(const bf16x8*)(Ab + (size_t)(mi * 16 + lr) * 1024 + e0 + lk * 8);
#pragma unroll
    for (int ni = 0; ni < 4; ++ni)
      bfv[ni] = *(const bf16x8*)(Bb + (size_t)(ni * 16 + lr) * 1024 + e0 + lk * 8);
#pragma unroll
    for (int mi = 0; mi < 4; ++mi)
#pragma unroll
      for (int ni = 0; ni < 4; ++ni)
        acc[mi][ni] = __builtin_amdgcn_mfma_f32_16x16x32_bf16(af[mi], bfv[ni], acc[mi][ni], 0, 0, 0);
  }
#pragma unroll
  for (int mi = 0; mi < 4; ++mi)
#pragma unroll
    for (int ni = 0; ni < 4; ++ni)
#pragma unroll
      for (int r = 0; r < 4; ++r)
        atomicAdd(&Msh[mi * 16 + lk * 4 + r][ni * 16 + lr], acc[mi][ni][r]);
  __syncthreads();

  for (int i = t; i < 64 * 64; i += 512) {
    int dp = i >> 6, k = i & 63;
    Mt[(size_t)bh * 4096 + i] = f2bf(Msh[k][dp] * SCALE_F);
  }
}

// ---------------- Amat_b[e][h*64+d'] = sum_k wqt[e][h*64+k] * Mt[b,h][d'][k] ----------------
__global__ __launch_bounds__(256) void make_amat(const unsigned short* __restrict__ wqt,
                                                 const unsigned short* __restrict__ Mt,
                                                 unsigned short* __restrict__ Amat) {
  const int t = threadIdx.x;
  const int w = t >> 6, l = t & 63;
  const int lr = l & 15, lk = l >> 4;
  const int et = blockIdx.x, h = blockIdx.y, b = blockIdx.z;
  const int e0 = et * 128 + w * 32;
  const unsigned short* Bb = Mt + (size_t)(b * 16 + h) * 4096;

  f32x4 acc[2][4] = {};
#pragma unroll
  for (int ks = 0; ks < 2; ++ks) {
    bf16x8 af[2], bfv[4];
#pragma unroll
    for (int mi = 0; mi < 2; ++mi)
      af[mi] = *(const bf16x8*)(wqt + (size_t)(e0 + mi * 16 + lr) * 1024 + h * 64 + ks * 32 + lk * 8);
#pragma unroll
    for (int ni = 0; ni < 4; ++ni)
      bfv[ni] = *(const bf16x8*)(Bb + (size_t)(ni * 16 + lr) * 64 + ks * 32 + lk * 8);
#pragma unroll
    for (int mi = 0; mi < 2; ++mi)
#pragma unroll
      for (int ni = 0; ni < 4; ++ni)
        acc[mi][ni] = __builtin_amdgcn_mfma_f32_16x16x32_bf16(af[mi], bfv[ni], acc[mi][ni], 0, 0, 0);
  }
#pragma unroll
  for (int mi = 0; mi < 2; ++mi)
#pragma unroll
    for (int ni = 0; ni < 4; ++ni)
#pragma unroll
      for (int r = 0; r < 4; ++r)
        Amat[(size_t)b * 1048576 + (size_t)(e0 + mi * 16 + lk * 4 + r) * 1024 + h * 64 + ni * 16 + lr]
            = f2bf(acc[mi][ni][r]);
}

// ---------------- launch ----------------
extern "C" void kernel_launch(void* const* d_in, const int* in_sizes, int n_in,
                              void* d_out, int out_size, void* d_ws, size_t ws_size,
                              hipStream_t stream) {
  const float* x    = (const float*)d_in[0];   // [4,2048,1024]
  const float* wqkv = (const float*)d_in[1];   // [3072,1024]
  const float* wo   = (const float*)d_in[2];   // [1024,1024]
  float* out = (float*)d_out;                  // [4,2048,1024] fp32

  char* ws = (char*)d_ws;
  const size_t MB = 1048576;
  unsigned short* xb   = (unsigned short*)(ws + 0);        // 16MB [8192][1024]
  unsigned short* xT   = (unsigned short*)(ws + 16 * MB);  // 16MB [1024][8192]
  unsigned short* wqt  = (unsigned short*)(ws + 32 * MB);  // 2MB  [1024 e][1024 i]
  unsigned short* wk   = (unsigned short*)(ws + 34 * MB);  // 2MB
  unsigned short* wv   = (unsigned short*)(ws + 36 * MB);  // 2MB
  unsigned short* wob  = (unsigned short*)(ws + 38 * MB);  // 2MB
  unsigned short* Gp   = (unsigned short*)(ws + 40 * MB);  // 32MB [4b][4p][1024][1024] (lower tiles only)
  unsigned short* G    = (unsigned short*)(ws + 72 * MB);  // 8MB  [4b][1024][1024]  -> peak 80MB
  // reuse dead regions:
  unsigned short* T1p  = (unsigned short*)(ws + 40 * MB);  // 16MB [4b][2p][1024][1024] (over dead Gp)
  unsigned short* Mt   = (unsigned short*)(ws + 56 * MB);  // 512KB [64 bh][64][64]
  unsigned short* Amat = (unsigned short*)(ws + 57 * MB);  // 8MB  [4b][1024 e][1024 i]
  unsigned short* Weff = (unsigned short*)(ws + 40 * MB);  // 8MB  [4b][1024 j][1024 e] (over dead T1p)

  const long M1 = 1048576;

  // converts
  cvt_x<<<dim3(128, 16), 256, 0, stream>>>(x, xb, xT);
  cvt_w<<<3072, 256, 0, stream>>>(wqkv, wo, wk, wv, wob);
  transpose_cvt<<<dim3(16, 16), 256, 0, stream>>>(wqkv, wqt, 1024, 192); // wqt[e][h*64+k]

  // G_b = x_b^T x_b : lower triangle, split-K x4 (576 blocks)
  gemm_tri<<<dim3(36, 1, 16), 256, 0, stream>>>(xT, Gp);
  mirror_reduce<<<dim3(36, 4), 256, 0, stream>>>(Gp, G);

  // T1_b = wk @ G_b (G symmetric -> bt form), split-K x2 (512 blocks); partials summed in make_mt
  gemm_bt<false><<<dim3(8, 8, 8), 256, 0, stream>>>(wk, 1024, 0, 512,
                                                    G, 1024, M1, 512,
                                                    (void*)T1p, 1024, 2 * M1, M1, 512, 2);

  // Mt[b,h] = SCALE * (T1_bh @ wv_h^T)^T   (accumulates both T1 partials)
  make_mt<<<64, 512, 0, stream>>>(T1p, wv, Mt);

  // Amat_b = Wq^T * blockdiag(SCALE*M_b)
  make_amat<<<dim3(8, 16, 4), 256, 0, stream>>>(wqt, Mt, Amat);

  // Weff_b[j][e] = sum_i wo[j][i] * Amat_b[e][i]   (single pass, 256 blocks = 1/CU)
  gemm_bt<false><<<dim3(8, 8, 4), 256, 0, stream>>>(wob, 1024, 0, 0,
                                                    Amat, 1024, M1, 0,
                                                    (void*)Weff, 1024, M1, 0, 1024, 1);

  // out_b = x_b @ Weff_b^T  (fp32 out)
  gemm_bt<true><<<dim3(8, 16, 4), 256, 0, stream>>>(xb, 1024, 2048 * 1024L, 0,
                                                    Weff, 1024, M1, 0,
                                                    (void*)out, 1024, 2048 * 1024L, 0, 1024, 1);
}

// Round 4
// 171.393 us; speedup vs baseline: 1.3183x; 1.3183x over previous
//
#include <hip/hip_runtime.h>
#include <hip/hip_bf16.h>
#include <cstdint>

// B=4, S=2048, E=1024, H=16, D=64, SCALE = 1/8
#define SCALE_F 0.125f

typedef __attribute__((ext_vector_type(8))) short bf16x8;
typedef __attribute__((ext_vector_type(4))) float f32x4;
typedef __attribute__((ext_vector_type(4))) unsigned short u16x4;
typedef __attribute__((ext_vector_type(8))) unsigned short u16x8;

typedef const __attribute__((address_space(1))) void glb_void;
typedef __attribute__((address_space(3))) void lds_void;

static __device__ __forceinline__ unsigned short f2bf(float f) {
  unsigned u = __builtin_bit_cast(unsigned, f);
  u = (u + 0x7fffu + ((u >> 16) & 1u)) >> 16;
  return (unsigned short)u;
}
static __device__ __forceinline__ float bf2f(unsigned short s) {
  unsigned u = ((unsigned)s) << 16;
  return __builtin_bit_cast(float, u);
}

// ---------------- fused x convert: xb (row-major bf16) + xT (transposed bf16) ----------------
__global__ __launch_bounds__(256) void cvt_x(const float* __restrict__ x,
                                             unsigned short* __restrict__ xb,
                                             unsigned short* __restrict__ xT) {
  __shared__ unsigned short lds[64][72];
  const int t = threadIdx.x;
  const int r0 = blockIdx.x * 64, c0 = blockIdx.y * 64;
#pragma unroll
  for (int pass = 0; pass < 4; ++pass) {
    int r = pass * 16 + (t >> 4);
    int c = (t & 15) * 4;
    float4 v = *(const float4*)(x + (size_t)(r0 + r) * 1024 + c0 + c);
    u16x4 o = { f2bf(v.x), f2bf(v.y), f2bf(v.z), f2bf(v.w) };
    *(u16x4*)(xb + (size_t)(r0 + r) * 1024 + c0 + c) = o;
#pragma unroll
    for (int j = 0; j < 4; ++j) {
      int C = c + j;
      lds[C][r ^ ((C & 7) << 3)] = o[j];
    }
  }
  __syncthreads();
#pragma unroll
  for (int pass = 0; pass < 2; ++pass) {
    int rr = pass * 32 + (t >> 3);
    int cc = (t & 7) * 8;
    u16x8 v = *(const u16x8*)&lds[rr][cc ^ ((rr & 7) << 3)];
    *(u16x8*)(xT + (size_t)(c0 + rr) * 8192 + r0 + cc) = v;
  }
}

// ---------------- merged weight converts: wk, wv, wob ----------------
__global__ __launch_bounds__(256) void cvt_w(const float* __restrict__ wqkv,
                                             const float* __restrict__ wo,
                                             unsigned short* __restrict__ wk,
                                             unsigned short* __restrict__ wv,
                                             unsigned short* __restrict__ wob) {
  int row = blockIdx.x;            // 0..3071
  const float* src;
  unsigned short* dst;
  if (row < 1024) {
    int h = row >> 6, k = row & 63;
    src = wqkv + (size_t)(h * 192 + 64 + k) * 1024;
    dst = wk + (size_t)row * 1024;
  } else if (row < 2048) {
    int local = row - 1024;
    int h = local >> 6, k = local & 63;
    src = wqkv + (size_t)(h * 192 + 128 + k) * 1024;
    dst = wv + (size_t)local * 1024;
  } else {
    int local = row - 2048;
    src = wo + (size_t)local * 1024;
    dst = wob + (size_t)local * 1024;
  }
  float4 v = *(const float4*)(src + threadIdx.x * 4);
  u16x4 o = { f2bf(v.x), f2bf(v.y), f2bf(v.z), f2bf(v.w) };
  *(u16x4*)(dst + threadIdx.x * 4) = o;
}

// transpose+cvt for wqt
__global__ __launch_bounds__(256) void transpose_cvt(const float* __restrict__ in,
                                                     unsigned short* __restrict__ out,
                                                     int ldo, int blk) {
  __shared__ unsigned short lds[64][72];
  const int t = threadIdx.x;
  const int r0 = blockIdx.x * 64, c0 = blockIdx.y * 64;
#pragma unroll
  for (int pass = 0; pass < 4; ++pass) {
    int r = pass * 16 + (t >> 4);
    int c = (t & 15) * 4;
    int gr = r0 + r;
    int srcRow = (gr >> 6) * blk + (gr & 63);
    float4 v = *(const float4*)(in + (size_t)srcRow * 1024 + c0 + c);
    lds[c + 0][r] = f2bf(v.x);
    lds[c + 1][r] = f2bf(v.y);
    lds[c + 2][r] = f2bf(v.z);
    lds[c + 3][r] = f2bf(v.w);
  }
  __syncthreads();
#pragma unroll
  for (int pass = 0; pass < 2; ++pass) {
    int rr = pass * 32 + (t >> 3);
    int cc = (t & 7) * 8;
    *(u16x8*)(out + (size_t)(c0 + rr) * ldo + r0 + cc) = *(const u16x8*)&lds[rr][cc];
  }
}

// ---------------- generic m97-style bt GEMM with batch/split-K ----------------
template<bool F32OUT>
__global__ __launch_bounds__(256) void gemm_bt(const unsigned short* __restrict__ A, int lda,
                                               long aB, long aP,
                                               const unsigned short* __restrict__ Bm, int ldb,
                                               long bB, long bP,
                                               void* __restrict__ Cv, int ldc,
                                               long cB, long cP,
                                               int K, int psplit) {
  __shared__ __align__(16) unsigned short Ash[128 * 32];
  __shared__ __align__(16) unsigned short Bsh[128 * 32];
  const int z = blockIdx.z;
  const int bb = z / psplit, pp = z % psplit;
  A  += (size_t)bb * aB + (size_t)pp * aP;
  Bm += (size_t)bb * bB + (size_t)pp * bP;
  const int t = threadIdx.x;
  const int w = t >> 6, l = t & 63;
  const int lr = l & 15, lk = l >> 4;
  const int m0 = blockIdx.y * 128, n0 = blockIdx.x * 128;
  const int wr = (w >> 1) * 64, wc = (w & 1) * 64;
  f32x4 acc[4][4] = {};

  for (int k0 = 0; k0 < K; k0 += 32) {
#pragma unroll
    for (int i = 0; i < 2; ++i) {
      const int c = i * 256 + t;
      const int row = c >> 2, kc = (c & 3) << 3;
      __builtin_amdgcn_global_load_lds(
          (glb_void*)(A + (size_t)(m0 + row) * lda + k0 + kc),
          (lds_void*)(Ash + i * 2048 + w * 512), 16, 0, 0);
      __builtin_amdgcn_global_load_lds(
          (glb_void*)(Bm + (size_t)(n0 + row) * ldb + k0 + kc),
          (lds_void*)(Bsh + i * 2048 + w * 512), 16, 0, 0);
    }
    __syncthreads();

    bf16x8 af[4], bfv[4];
#pragma unroll
    for (int mi = 0; mi < 4; ++mi)
      af[mi] = *(const bf16x8*)(Ash + (wr + mi * 16 + lr) * 32 + lk * 8);
#pragma unroll
    for (int ni = 0; ni < 4; ++ni)
      bfv[ni] = *(const bf16x8*)(Bsh + (wc + ni * 16 + lr) * 32 + lk * 8);
#pragma unroll
    for (int mi = 0; mi < 4; ++mi)
#pragma unroll
      for (int ni = 0; ni < 4; ++ni)
        acc[mi][ni] = __builtin_amdgcn_mfma_f32_16x16x32_bf16(af[mi], bfv[ni], acc[mi][ni], 0, 0, 0);
    __syncthreads();
  }

#pragma unroll
  for (int mi = 0; mi < 4; ++mi)
#pragma unroll
    for (int ni = 0; ni < 4; ++ni)
#pragma unroll
      for (int r = 0; r < 4; ++r) {
        const size_t row = (size_t)(m0 + wr + mi * 16 + lk * 4 + r);
        const size_t col = (size_t)(n0 + wc + ni * 16 + lr);
        if constexpr (F32OUT)
          ((float*)Cv)[(size_t)bb * cB + (size_t)pp * cP + row * ldc + col] = acc[mi][ni][r];
        else
          ((unsigned short*)Cv)[(size_t)bb * cB + (size_t)pp * cP + row * ldc + col] = f2bf(acc[mi][ni][r]);
      }
}

// ---------------- triangular Gram GEMM: Gp[z] tile(mt,nt), mt>=nt, K=512 ----------------
__global__ __launch_bounds__(256) void gemm_tri(const unsigned short* __restrict__ xT,
                                                unsigned short* __restrict__ Gp) {
  __shared__ __align__(16) unsigned short Ash[128 * 32];
  __shared__ __align__(16) unsigned short Bsh[128 * 32];
  int ti = blockIdx.x;
  int mt = 0, accum = 0;
  while (accum + mt + 1 <= ti) { accum += mt + 1; ++mt; }
  int nt = ti - accum;
  const int z = blockIdx.z;
  const int b = z >> 2, p = z & 3;
  const unsigned short* base = xT + (size_t)b * 2048 + (size_t)p * 512;

  const int t = threadIdx.x;
  const int w = t >> 6, l = t & 63;
  const int lr = l & 15, lk = l >> 4;
  const int m0 = mt * 128, n0 = nt * 128;
  const int wr = (w >> 1) * 64, wc = (w & 1) * 64;
  f32x4 acc[4][4] = {};

  for (int k0 = 0; k0 < 512; k0 += 32) {
#pragma unroll
    for (int i = 0; i < 2; ++i) {
      const int c = i * 256 + t;
      const int row = c >> 2, kc = (c & 3) << 3;
      __builtin_amdgcn_global_load_lds(
          (glb_void*)(base + (size_t)(m0 + row) * 8192 + k0 + kc),
          (lds_void*)(Ash + i * 2048 + w * 512), 16, 0, 0);
      __builtin_amdgcn_global_load_lds(
          (glb_void*)(base + (size_t)(n0 + row) * 8192 + k0 + kc),
          (lds_void*)(Bsh + i * 2048 + w * 512), 16, 0, 0);
    }
    __syncthreads();

    bf16x8 af[4], bfv[4];
#pragma unroll
    for (int mi = 0; mi < 4; ++mi)
      af[mi] = *(const bf16x8*)(Ash + (wr + mi * 16 + lr) * 32 + lk * 8);
#pragma unroll
    for (int ni = 0; ni < 4; ++ni)
      bfv[ni] = *(const bf16x8*)(Bsh + (wc + ni * 16 + lr) * 32 + lk * 8);
#pragma unroll
    for (int mi = 0; mi < 4; ++mi)
#pragma unroll
      for (int ni = 0; ni < 4; ++ni)
        acc[mi][ni] = __builtin_amdgcn_mfma_f32_16x16x32_bf16(af[mi], bfv[ni], acc[mi][ni], 0, 0, 0);
    __syncthreads();
  }

  unsigned short* out = Gp + (size_t)z * 1048576;
#pragma unroll
  for (int mi = 0; mi < 4; ++mi)
#pragma unroll
    for (int ni = 0; ni < 4; ++ni)
#pragma unroll
      for (int r = 0; r < 4; ++r)
        out[(size_t)(m0 + wr + mi * 16 + lk * 4 + r) * 1024 + n0 + wc + ni * 16 + lr]
            = f2bf(acc[mi][ni][r]);
}

// ---------------- mirror+reduce via LDS transpose: G[b] = sum_p Gp[b,p], both triangles ----
__global__ __launch_bounds__(256) void mirror_reduce(const unsigned short* __restrict__ Gp,
                                                     unsigned short* __restrict__ G) {
  __shared__ unsigned short ldsT[128][128];  // logical ldsT[col][row], row-index XOR-swizzled
  int ti = blockIdx.x;
  int mt = 0, accum = 0;
  while (accum + mt + 1 <= ti) { accum += mt + 1; ++mt; }
  int nt = ti - accum;
  const int b = blockIdx.y;
  const int m0 = mt * 128, n0 = nt * 128;
  const unsigned short* base = Gp + (size_t)b * 4 * 1048576;
  unsigned short* Gb = G + (size_t)b * 1048576;
  const int t = threadIdx.x;

  // direct tile (mt,nt): coalesced 4-partial reduce + stash transposed into LDS
#pragma unroll
  for (int pass = 0; pass < 8; ++pass) {
    int idx = pass * 2048 + t * 8;
    int r = idx >> 7, c = idx & 127;
    float s[8] = {};
#pragma unroll
    for (int p = 0; p < 4; ++p) {
      u16x8 v = *(const u16x8*)(base + (size_t)p * 1048576 + (size_t)(m0 + r) * 1024 + n0 + c);
#pragma unroll
      for (int j = 0; j < 8; ++j) s[j] += bf2f(v[j]);
    }
    u16x8 o;
#pragma unroll
    for (int j = 0; j < 8; ++j) o[j] = f2bf(s[j]);
    *(u16x8*)(Gb + (size_t)(m0 + r) * 1024 + n0 + c) = o;
#pragma unroll
    for (int j = 0; j < 8; ++j) {
      int col = c + j;
      ldsT[col][r ^ (((col >> 3) & 7) << 3)] = o[j];
    }
  }

  // mirrored tile (nt,mt): G[n0+rr][m0+cc+j] = Gsum[cc+j][rr] = ldsT[rr][cc+j]
  if (mt != nt) {
    __syncthreads();
#pragma unroll
    for (int pass = 0; pass < 8; ++pass) {
      int idx = pass * 2048 + t * 8;
      int rr = idx >> 7, cc = idx & 127;
      u16x8 v = *(const u16x8*)&ldsT[rr][cc ^ (((rr >> 3) & 7) << 3)];
      *(u16x8*)(Gb + (size_t)(n0 + rr) * 1024 + m0 + cc) = v;
    }
  }
}

// ---------------- Mp[bh][ep][k][d'] = sum over (p, e-span) of T1p * wv  (f32 partials) ----
__global__ __launch_bounds__(256) void mt_partial(const unsigned short* __restrict__ T1p,
                                                  const unsigned short* __restrict__ wv,
                                                  float* __restrict__ Mp) {
  __shared__ float Msh[4096];   // [k][d'] linear
  const int t = threadIdx.x;
  const int w = t >> 6, l = t & 63;
  const int lr = l & 15, lk = l >> 4;
  const int bh = blockIdx.x, ep = blockIdx.y;
  const int b = bh >> 4, h = bh & 15;
  const int p = w >> 1, half = w & 1;

  for (int i = t; i < 4096; i += 256) Msh[i] = 0.f;
  __syncthreads();

  const unsigned short* Ab = T1p + (size_t)(b * 2 + p) * 1048576 + (size_t)(h * 64) * 1024;
  const unsigned short* Bb = wv + (size_t)(h * 64) * 1024;
  f32x4 acc[4][4] = {};
  const int ebeg = ep * 256 + half * 128;
#pragma unroll
  for (int e0 = ebeg; e0 < ebeg + 128; e0 += 32) {
    bf16x8 af[4], bfv[4];
#pragma unroll
    for (int mi = 0; mi < 4; ++mi)
      af[mi] = *(const bf16x8*)(Ab + (size_t)(mi * 16 + lr) * 1024 + e0 + lk * 8);
#pragma unroll
    for (int ni = 0; ni < 4; ++ni)
      bfv[ni] = *(const bf16x8*)(Bb + (size_t)(ni * 16 + lr) * 1024 + e0 + lk * 8);
#pragma unroll
    for (int mi = 0; mi < 4; ++mi)
#pragma unroll
      for (int ni = 0; ni < 4; ++ni)
        acc[mi][ni] = __builtin_amdgcn_mfma_f32_16x16x32_bf16(af[mi], bfv[ni], acc[mi][ni], 0, 0, 0);
  }
#pragma unroll
  for (int mi = 0; mi < 4; ++mi)
#pragma unroll
    for (int ni = 0; ni < 4; ++ni)
#pragma unroll
      for (int r = 0; r < 4; ++r)
        atomicAdd(&Msh[(mi * 16 + lk * 4 + r) * 64 + ni * 16 + lr], acc[mi][ni][r]);
  __syncthreads();

  float* out = Mp + ((size_t)bh * 4 + ep) * 4096;
  for (int i = t * 4; i < 4096; i += 1024)
    *(float4*)(out + i) = *(const float4*)&Msh[i];
}

// ---------------- Mt[bh][d'][k] = bf16( SCALE * sum_ep Mp[bh][ep][k][d'] ) ----------------
__global__ __launch_bounds__(256) void mt_reduce(const float* __restrict__ Mp,
                                                 unsigned short* __restrict__ Mt) {
  __shared__ float Msh[4096];   // summed [k][d']
  const int t = threadIdx.x;
  const int bh = blockIdx.x;
  const float* base = Mp + (size_t)bh * 4 * 4096;
  for (int i = t * 4; i < 4096; i += 1024) {
    float4 s = *(const float4*)(base + i);
#pragma unroll
    for (int p = 1; p < 4; ++p) {
      float4 v = *(const float4*)(base + p * 4096 + i);
      s.x += v.x; s.y += v.y; s.z += v.z; s.w += v.w;
    }
    *(float4*)&Msh[i] = s;
  }
  __syncthreads();
#pragma unroll
  for (int pass = 0; pass < 2; ++pass) {
    int i = pass * 2048 + t * 8;       // i = dp*64 + k
    int dp = i >> 6, k = i & 63;
    u16x8 o;
#pragma unroll
    for (int j = 0; j < 8; ++j) o[j] = f2bf(Msh[(k + j) * 64 + dp] * SCALE_F);
    *(u16x8*)(Mt + (size_t)bh * 4096 + i) = o;
  }
}

// ---------------- Amat_b[e][h*64+d'] = sum_k wqt[e][h*64+k] * Mt[b,h][d'][k] ----------------
__global__ __launch_bounds__(256) void make_amat(const unsigned short* __restrict__ wqt,
                                                 const unsigned short* __restrict__ Mt,
                                                 unsigned short* __restrict__ Amat) {
  const int t = threadIdx.x;
  const int w = t >> 6, l = t & 63;
  const int lr = l & 15, lk = l >> 4;
  const int et = blockIdx.x, h = blockIdx.y, b = blockIdx.z;
  const int e0 = et * 128 + w * 32;
  const unsigned short* Bb = Mt + (size_t)(b * 16 + h) * 4096;

  f32x4 acc[2][4] = {};
#pragma unroll
  for (int ks = 0; ks < 2; ++ks) {
    bf16x8 af[2], bfv[4];
#pragma unroll
    for (int mi = 0; mi < 2; ++mi)
      af[mi] = *(const bf16x8*)(wqt + (size_t)(e0 + mi * 16 + lr) * 1024 + h * 64 + ks * 32 + lk * 8);
#pragma unroll
    for (int ni = 0; ni < 4; ++ni)
      bfv[ni] = *(const bf16x8*)(Bb + (size_t)(ni * 16 + lr) * 64 + ks * 32 + lk * 8);
#pragma unroll
    for (int mi = 0; mi < 2; ++mi)
#pragma unroll
      for (int ni = 0; ni < 4; ++ni)
        acc[mi][ni] = __builtin_amdgcn_mfma_f32_16x16x32_bf16(af[mi], bfv[ni], acc[mi][ni], 0, 0, 0);
  }
#pragma unroll
  for (int mi = 0; mi < 2; ++mi)
#pragma unroll
    for (int ni = 0; ni < 4; ++ni)
#pragma unroll
      for (int r = 0; r < 4; ++r)
        Amat[(size_t)b * 1048576 + (size_t)(e0 + mi * 16 + lk * 4 + r) * 1024 + h * 64 + ni * 16 + lr]
            = f2bf(acc[mi][ni][r]);
}

// ---------------- launch ----------------
extern "C" void kernel_launch(void* const* d_in, const int* in_sizes, int n_in,
                              void* d_out, int out_size, void* d_ws, size_t ws_size,
                              hipStream_t stream) {
  const float* x    = (const float*)d_in[0];   // [4,2048,1024]
  const float* wqkv = (const float*)d_in[1];   // [3072,1024]
  const float* wo   = (const float*)d_in[2];   // [1024,1024]
  float* out = (float*)d_out;                  // [4,2048,1024] fp32

  char* ws = (char*)d_ws;
  const size_t MB = 1048576;
  unsigned short* xb   = (unsigned short*)(ws + 0);        // 16MB [8192][1024]
  unsigned short* xT   = (unsigned short*)(ws + 16 * MB);  // 16MB [1024][8192]
  unsigned short* wqt  = (unsigned short*)(ws + 32 * MB);  // 2MB
  unsigned short* wk   = (unsigned short*)(ws + 34 * MB);  // 2MB
  unsigned short* wv   = (unsigned short*)(ws + 36 * MB);  // 2MB
  unsigned short* wob  = (unsigned short*)(ws + 38 * MB);  // 2MB
  unsigned short* Gp   = (unsigned short*)(ws + 40 * MB);  // 32MB [4b][4p][1024][1024] (lower tiles)
  unsigned short* G    = (unsigned short*)(ws + 72 * MB);  // 8MB  [4b][1024][1024]  -> peak 80MB
  // reuse dead regions:
  unsigned short* T1p  = (unsigned short*)(ws + 40 * MB);  // 16MB [4b][2p][1024][1024] (over dead Gp)
  float*          Mp   = (float*)        (ws + 56 * MB);   // 4MB  [64 bh][4 ep][64][64] f32
  unsigned short* Mt   = (unsigned short*)(ws + 60 * MB);  // 512KB [64 bh][64][64]
  unsigned short* Amat = (unsigned short*)(ws + 61 * MB);  // 8MB  [4b][1024 e][1024 i]
  unsigned short* Weff = (unsigned short*)(ws + 40 * MB);  // 8MB  (over dead T1p)

  const long M1 = 1048576;

  // converts
  cvt_x<<<dim3(128, 16), 256, 0, stream>>>(x, xb, xT);
  cvt_w<<<3072, 256, 0, stream>>>(wqkv, wo, wk, wv, wob);
  transpose_cvt<<<dim3(16, 16), 256, 0, stream>>>(wqkv, wqt, 1024, 192); // wqt[e][h*64+k]

  // G_b = x_b^T x_b : lower triangle, split-K x4 (576 blocks)
  gemm_tri<<<dim3(36, 1, 16), 256, 0, stream>>>(xT, Gp);
  mirror_reduce<<<dim3(36, 4), 256, 0, stream>>>(Gp, G);

  // T1_b = wk @ G_b (G symmetric), split-K x2 (512 blocks); partials summed in mt_partial
  gemm_bt<false><<<dim3(8, 8, 8), 256, 0, stream>>>(wk, 1024, 0, 512,
                                                    G, 1024, M1, 512,
                                                    (void*)T1p, 1024, 2 * M1, M1, 512, 2);

  // M partials: 256 blocks, 4 waves each (K-partial x e-half), f32 out
  mt_partial<<<dim3(64, 4), 256, 0, stream>>>(T1p, wv, Mp);
  // reduce 4 e-quarters, transpose, scale -> Mt[bh][d'][k] bf16
  mt_reduce<<<64, 256, 0, stream>>>(Mp, Mt);

  // Amat_b = Wq^T * blockdiag(SCALE*M_b)
  make_amat<<<dim3(8, 16, 4), 256, 0, stream>>>(wqt, Mt, Amat);

  // Weff_b[j][e] = sum_i wo[j][i] * Amat_b[e][i]   (256 blocks = 1/CU)
  gemm_bt<false><<<dim3(8, 8, 4), 256, 0, stream>>>(wob, 1024, 0, 0,
                                                    Amat, 1024, M1, 0,
                                                    (void*)Weff, 1024, M1, 0, 1024, 1);

  // out_b = x_b @ Weff_b^T  (fp32 out)
  gemm_bt<true><<<dim3(8, 16, 4), 256, 0, stream>>>(xb, 1024, 2048 * 1024L, 0,
                                                    Weff, 1024, M1, 0,
                                                    (void*)out, 1024, 2048 * 1024L, 0, 1024, 1);
}

// Round 5
// 168.646 us; speedup vs baseline: 1.3398x; 1.0163x over previous
//
#include <hip/hip_runtime.h>
#include <hip/hip_bf16.h>
#include <cstdint>

// B=4, S=2048, E=1024, H=16, D=64, SCALE = 1/8
#define SCALE_F 0.125f

typedef __attribute__((ext_vector_type(8))) short bf16x8;
typedef __attribute__((ext_vector_type(4))) float f32x4;
typedef __attribute__((ext_vector_type(4))) unsigned short u16x4;
typedef __attribute__((ext_vector_type(8))) unsigned short u16x8;

typedef const __attribute__((address_space(1))) void glb_void;
typedef __attribute__((address_space(3))) void lds_void;

static __device__ __forceinline__ unsigned short f2bf(float f) {
  unsigned u = __builtin_bit_cast(unsigned, f);
  u = (u + 0x7fffu + ((u >> 16) & 1u)) >> 16;
  return (unsigned short)u;
}
static __device__ __forceinline__ float bf2f(unsigned short s) {
  unsigned u = ((unsigned)s) << 16;
  return __builtin_bit_cast(float, u);
}

// ---------------- fused prep: all converts in ONE kernel ----------------
// bid <  2048 : cvt_x    -> xb (row-major bf16) + xT (transposed bf16)
// bid <  5120 : cvt_w    -> wk, wv, wob row gathers
// bid <  5376 : wqt      -> transpose+gather of wqkv Q rows
__global__ __launch_bounds__(256) void prep(const float* __restrict__ x,
                                            const float* __restrict__ wqkv,
                                            const float* __restrict__ wo,
                                            unsigned short* __restrict__ xb,
                                            unsigned short* __restrict__ xT,
                                            unsigned short* __restrict__ wqt,
                                            unsigned short* __restrict__ wk,
                                            unsigned short* __restrict__ wv,
                                            unsigned short* __restrict__ wob) {
  __shared__ unsigned short lds[64][72];
  const int t = threadIdx.x;
  const int bid = blockIdx.x;

  if (bid < 2048) {
    // ---- cvt_x: x[8192][1024] -> xb + xT ----
    const int r0 = (bid & 127) * 64, c0 = (bid >> 7) * 64;
#pragma unroll
    for (int pass = 0; pass < 4; ++pass) {
      int r = pass * 16 + (t >> 4);
      int c = (t & 15) * 4;
      float4 v = *(const float4*)(x + (size_t)(r0 + r) * 1024 + c0 + c);
      u16x4 o = { f2bf(v.x), f2bf(v.y), f2bf(v.z), f2bf(v.w) };
      *(u16x4*)(xb + (size_t)(r0 + r) * 1024 + c0 + c) = o;
#pragma unroll
      for (int j = 0; j < 4; ++j) {
        int C = c + j;
        lds[C][r ^ ((C & 7) << 3)] = o[j];
      }
    }
    __syncthreads();
#pragma unroll
    for (int pass = 0; pass < 2; ++pass) {
      int rr = pass * 32 + (t >> 3);
      int cc = (t & 7) * 8;
      u16x8 v = *(const u16x8*)&lds[rr][cc ^ ((rr & 7) << 3)];
      *(u16x8*)(xT + (size_t)(c0 + rr) * 8192 + r0 + cc) = v;
    }
  } else if (bid < 5120) {
    // ---- cvt_w: row gathers ----
    int row = bid - 2048;            // 0..3071
    const float* src;
    unsigned short* dst;
    if (row < 1024) {
      int h = row >> 6, k = row & 63;
      src = wqkv + (size_t)(h * 192 + 64 + k) * 1024;
      dst = wk + (size_t)row * 1024;
    } else if (row < 2048) {
      int local = row - 1024;
      int h = local >> 6, k = local & 63;
      src = wqkv + (size_t)(h * 192 + 128 + k) * 1024;
      dst = wv + (size_t)local * 1024;
    } else {
      int local = row - 2048;
      src = wo + (size_t)local * 1024;
      dst = wob + (size_t)local * 1024;
    }
    float4 v = *(const float4*)(src + t * 4);
    u16x4 o = { f2bf(v.x), f2bf(v.y), f2bf(v.z), f2bf(v.w) };
    *(u16x4*)(dst + t * 4) = o;
  } else {
    // ---- wqt transpose: wqt[e][h*64+k] = bf16(wqkv[h*192+k][e]) ----
    int tid = bid - 5120;            // 0..255, orig grid (16,16)
    const int r0 = (tid & 15) * 64, c0 = (tid >> 4) * 64;
#pragma unroll
    for (int pass = 0; pass < 4; ++pass) {
      int r = pass * 16 + (t >> 4);
      int c = (t & 15) * 4;
      int gr = r0 + r;
      int srcRow = (gr >> 6) * 192 + (gr & 63);
      float4 v = *(const float4*)(wqkv + (size_t)srcRow * 1024 + c0 + c);
      lds[c + 0][r] = f2bf(v.x);
      lds[c + 1][r] = f2bf(v.y);
      lds[c + 2][r] = f2bf(v.z);
      lds[c + 3][r] = f2bf(v.w);
    }
    __syncthreads();
#pragma unroll
    for (int pass = 0; pass < 2; ++pass) {
      int rr = pass * 32 + (t >> 3);
      int cc = (t & 7) * 8;
      *(u16x8*)(wqt + (size_t)(c0 + rr) * 1024 + r0 + cc) = *(const u16x8*)&lds[rr][cc];
    }
  }
}

// ---------------- generic m97-style bt GEMM with batch/split-K ----------------
template<bool F32OUT>
__global__ __launch_bounds__(256) void gemm_bt(const unsigned short* __restrict__ A, int lda,
                                               long aB, long aP,
                                               const unsigned short* __restrict__ Bm, int ldb,
                                               long bB, long bP,
                                               void* __restrict__ Cv, int ldc,
                                               long cB, long cP,
                                               int K, int psplit) {
  __shared__ __align__(16) unsigned short Ash[128 * 32];
  __shared__ __align__(16) unsigned short Bsh[128 * 32];
  const int z = blockIdx.z;
  const int bb = z / psplit, pp = z % psplit;
  A  += (size_t)bb * aB + (size_t)pp * aP;
  Bm += (size_t)bb * bB + (size_t)pp * bP;
  const int t = threadIdx.x;
  const int w = t >> 6, l = t & 63;
  const int lr = l & 15, lk = l >> 4;
  const int m0 = blockIdx.y * 128, n0 = blockIdx.x * 128;
  const int wr = (w >> 1) * 64, wc = (w & 1) * 64;
  f32x4 acc[4][4] = {};

  for (int k0 = 0; k0 < K; k0 += 32) {
#pragma unroll
    for (int i = 0; i < 2; ++i) {
      const int c = i * 256 + t;
      const int row = c >> 2, kc = (c & 3) << 3;
      __builtin_amdgcn_global_load_lds(
          (glb_void*)(A + (size_t)(m0 + row) * lda + k0 + kc),
          (lds_void*)(Ash + i * 2048 + w * 512), 16, 0, 0);
      __builtin_amdgcn_global_load_lds(
          (glb_void*)(Bm + (size_t)(n0 + row) * ldb + k0 + kc),
          (lds_void*)(Bsh + i * 2048 + w * 512), 16, 0, 0);
    }
    __syncthreads();

    bf16x8 af[4], bfv[4];
#pragma unroll
    for (int mi = 0; mi < 4; ++mi)
      af[mi] = *(const bf16x8*)(Ash + (wr + mi * 16 + lr) * 32 + lk * 8);
#pragma unroll
    for (int ni = 0; ni < 4; ++ni)
      bfv[ni] = *(const bf16x8*)(Bsh + (wc + ni * 16 + lr) * 32 + lk * 8);
#pragma unroll
    for (int mi = 0; mi < 4; ++mi)
#pragma unroll
      for (int ni = 0; ni < 4; ++ni)
        acc[mi][ni] = __builtin_amdgcn_mfma_f32_16x16x32_bf16(af[mi], bfv[ni], acc[mi][ni], 0, 0, 0);
    __syncthreads();
  }

#pragma unroll
  for (int mi = 0; mi < 4; ++mi)
#pragma unroll
    for (int ni = 0; ni < 4; ++ni)
#pragma unroll
      for (int r = 0; r < 4; ++r) {
        const size_t row = (size_t)(m0 + wr + mi * 16 + lk * 4 + r);
        const size_t col = (size_t)(n0 + wc + ni * 16 + lr);
        if constexpr (F32OUT)
          ((float*)Cv)[(size_t)bb * cB + (size_t)pp * cP + row * ldc + col] = acc[mi][ni][r];
        else
          ((unsigned short*)Cv)[(size_t)bb * cB + (size_t)pp * cP + row * ldc + col] = f2bf(acc[mi][ni][r]);
      }
}

// ---------------- triangular Gram GEMM: Gp[z] tile(mt,nt), mt>=nt, K=512 ----------------
__global__ __launch_bounds__(256) void gemm_tri(const unsigned short* __restrict__ xT,
                                                unsigned short* __restrict__ Gp) {
  __shared__ __align__(16) unsigned short Ash[128 * 32];
  __shared__ __align__(16) unsigned short Bsh[128 * 32];
  int ti = blockIdx.x;
  int mt = 0, accum = 0;
  while (accum + mt + 1 <= ti) { accum += mt + 1; ++mt; }
  int nt = ti - accum;
  const int z = blockIdx.z;
  const int b = z >> 2, p = z & 3;
  const unsigned short* base = xT + (size_t)b * 2048 + (size_t)p * 512;

  const int t = threadIdx.x;
  const int w = t >> 6, l = t & 63;
  const int lr = l & 15, lk = l >> 4;
  const int m0 = mt * 128, n0 = nt * 128;
  const int wr = (w >> 1) * 64, wc = (w & 1) * 64;
  f32x4 acc[4][4] = {};

  for (int k0 = 0; k0 < 512; k0 += 32) {
#pragma unroll
    for (int i = 0; i < 2; ++i) {
      const int c = i * 256 + t;
      const int row = c >> 2, kc = (c & 3) << 3;
      __builtin_amdgcn_global_load_lds(
          (glb_void*)(base + (size_t)(m0 + row) * 8192 + k0 + kc),
          (lds_void*)(Ash + i * 2048 + w * 512), 16, 0, 0);
      __builtin_amdgcn_global_load_lds(
          (glb_void*)(base + (size_t)(n0 + row) * 8192 + k0 + kc),
          (lds_void*)(Bsh + i * 2048 + w * 512), 16, 0, 0);
    }
    __syncthreads();

    bf16x8 af[4], bfv[4];
#pragma unroll
    for (int mi = 0; mi < 4; ++mi)
      af[mi] = *(const bf16x8*)(Ash + (wr + mi * 16 + lr) * 32 + lk * 8);
#pragma unroll
    for (int ni = 0; ni < 4; ++ni)
      bfv[ni] = *(const bf16x8*)(Bsh + (wc + ni * 16 + lr) * 32 + lk * 8);
#pragma unroll
    for (int mi = 0; mi < 4; ++mi)
#pragma unroll
      for (int ni = 0; ni < 4; ++ni)
        acc[mi][ni] = __builtin_amdgcn_mfma_f32_16x16x32_bf16(af[mi], bfv[ni], acc[mi][ni], 0, 0, 0);
    __syncthreads();
  }

  unsigned short* out = Gp + (size_t)z * 1048576;
#pragma unroll
  for (int mi = 0; mi < 4; ++mi)
#pragma unroll
    for (int ni = 0; ni < 4; ++ni)
#pragma unroll
      for (int r = 0; r < 4; ++r)
        out[(size_t)(m0 + wr + mi * 16 + lk * 4 + r) * 1024 + n0 + wc + ni * 16 + lr]
            = f2bf(acc[mi][ni][r]);
}

// ---------------- mirror+reduce via LDS transpose: G[b] = sum_p Gp[b,p], both triangles ----
__global__ __launch_bounds__(256) void mirror_reduce(const unsigned short* __restrict__ Gp,
                                                     unsigned short* __restrict__ G) {
  __shared__ unsigned short ldsT[128][128];
  int ti = blockIdx.x;
  int mt = 0, accum = 0;
  while (accum + mt + 1 <= ti) { accum += mt + 1; ++mt; }
  int nt = ti - accum;
  const int b = blockIdx.y;
  const int m0 = mt * 128, n0 = nt * 128;
  const unsigned short* base = Gp + (size_t)b * 4 * 1048576;
  unsigned short* Gb = G + (size_t)b * 1048576;
  const int t = threadIdx.x;

#pragma unroll
  for (int pass = 0; pass < 8; ++pass) {
    int idx = pass * 2048 + t * 8;
    int r = idx >> 7, c = idx & 127;
    float s[8] = {};
#pragma unroll
    for (int p = 0; p < 4; ++p) {
      u16x8 v = *(const u16x8*)(base + (size_t)p * 1048576 + (size_t)(m0 + r) * 1024 + n0 + c);
#pragma unroll
      for (int j = 0; j < 8; ++j) s[j] += bf2f(v[j]);
    }
    u16x8 o;
#pragma unroll
    for (int j = 0; j < 8; ++j) o[j] = f2bf(s[j]);
    *(u16x8*)(Gb + (size_t)(m0 + r) * 1024 + n0 + c) = o;
#pragma unroll
    for (int j = 0; j < 8; ++j) {
      int col = c + j;
      ldsT[col][r ^ (((col >> 3) & 7) << 3)] = o[j];
    }
  }

  if (mt != nt) {
    __syncthreads();
#pragma unroll
    for (int pass = 0; pass < 8; ++pass) {
      int idx = pass * 2048 + t * 8;
      int rr = idx >> 7, cc = idx & 127;
      u16x8 v = *(const u16x8*)&ldsT[rr][cc ^ (((rr >> 3) & 7) << 3)];
      *(u16x8*)(Gb + (size_t)(n0 + rr) * 1024 + m0 + cc) = v;
    }
  }
}

// ---------------- Mp[bh][ep][k][d'] = sum over (p, e-span) of T1p * wv  (f32 partials) ----
__global__ __launch_bounds__(256) void mt_partial(const unsigned short* __restrict__ T1p,
                                                  const unsigned short* __restrict__ wv,
                                                  float* __restrict__ Mp) {
  __shared__ float Msh[4096];   // [k][d'] linear
  const int t = threadIdx.x;
  const int w = t >> 6, l = t & 63;
  const int lr = l & 15, lk = l >> 4;
  const int bh = blockIdx.x, ep = blockIdx.y;
  const int b = bh >> 4, h = bh & 15;
  const int p = w >> 1, half = w & 1;

  for (int i = t; i < 4096; i += 256) Msh[i] = 0.f;
  __syncthreads();

  const unsigned short* Ab = T1p + (size_t)(b * 2 + p) * 1048576 + (size_t)(h * 64) * 1024;
  const unsigned short* Bb = wv + (size_t)(h * 64) * 1024;
  f32x4 acc[4][4] = {};
  const int ebeg = ep * 256 + half * 128;
#pragma unroll
  for (int e0 = ebeg; e0 < ebeg + 128; e0 += 32) {
    bf16x8 af[4], bfv[4];
#pragma unroll
    for (int mi = 0; mi < 4; ++mi)
      af[mi] = *(const bf16x8*)(Ab + (size_t)(mi * 16 + lr) * 1024 + e0 + lk * 8);
#pragma unroll
    for (int ni = 0; ni < 4; ++ni)
      bfv[ni] = *(const bf16x8*)(Bb + (size_t)(ni * 16 + lr) * 1024 + e0 + lk * 8);
#pragma unroll
    for (int mi = 0; mi < 4; ++mi)
#pragma unroll
      for (int ni = 0; ni < 4; ++ni)
        acc[mi][ni] = __builtin_amdgcn_mfma_f32_16x16x32_bf16(af[mi], bfv[ni], acc[mi][ni], 0, 0, 0);
  }
#pragma unroll
  for (int mi = 0; mi < 4; ++mi)
#pragma unroll
    for (int ni = 0; ni < 4; ++ni)
#pragma unroll
      for (int r = 0; r < 4; ++r)
        atomicAdd(&Msh[(mi * 16 + lk * 4 + r) * 64 + ni * 16 + lr], acc[mi][ni][r]);
  __syncthreads();

  float* out = Mp + ((size_t)bh * 4 + ep) * 4096;
  for (int i = t * 4; i < 4096; i += 1024)
    *(float4*)(out + i) = *(const float4*)&Msh[i];
}

// ---------------- fused: reduce Mp -> Mt (LDS) -> Amat slice ----------------
// grid (8 et, 64 bh): Amat_b[e0..e0+128)[h*64+d'] = sum_k wqt[e][h*64+k] * Mt[bh][d'][k]
__global__ __launch_bounds__(256) void amat_fused(const float* __restrict__ Mp,
                                                  const unsigned short* __restrict__ wqt,
                                                  unsigned short* __restrict__ Amat) {
  __shared__ float Msh[64 * 68];            // [k][dp], padded row 68
  __shared__ unsigned short MtSh[64][80];   // [dp][k], padded row 80 (16B-aligned rows)
  const int t = threadIdx.x;
  const int et = blockIdx.x, bh = blockIdx.y;
  const int b = bh >> 4, h = bh & 15;

  // reduce 4 ep-partials (f32, exact)
  const float* base = Mp + (size_t)bh * 16384;
  for (int i = t * 4; i < 4096; i += 1024) {
    float4 s = *(const float4*)(base + i);
#pragma unroll
    for (int p = 1; p < 4; ++p) {
      float4 v = *(const float4*)(base + p * 4096 + i);
      s.x += v.x; s.y += v.y; s.z += v.z; s.w += v.w;
    }
    int k = i >> 6, dp = i & 63;
    *(float4*)&Msh[k * 68 + dp] = s;
  }
  __syncthreads();

  // Mt[dp][k] = bf16(SCALE * M[k][dp])
  for (int i = t; i < 4096; i += 256) {
    int dp = i >> 6, k = i & 63;
    MtSh[dp][k] = f2bf(Msh[k * 68 + dp] * SCALE_F);
  }
  __syncthreads();

  // Amat slice: A = wqt[e0.., h*64..], B = MtSh
  const int w = t >> 6, l = t & 63;
  const int lr = l & 15, lk = l >> 4;
  const int e0 = et * 128 + w * 32;

  f32x4 acc[2][4] = {};
#pragma unroll
  for (int ks = 0; ks < 2; ++ks) {
    bf16x8 af[2], bfv[4];
#pragma unroll
    for (int mi = 0; mi < 2; ++mi)
      af[mi] = *(const bf16x8*)(wqt + (size_t)(e0 + mi * 16 + lr) * 1024 + h * 64 + ks * 32 + lk * 8);
#pragma unroll
    for (int ni = 0; ni < 4; ++ni)
      bfv[ni] = *(const bf16x8*)(&MtSh[ni * 16 + lr][ks * 32 + lk * 8]);
#pragma unroll
    for (int mi = 0; mi < 2; ++mi)
#pragma unroll
      for (int ni = 0; ni < 4; ++ni)
        acc[mi][ni] = __builtin_amdgcn_mfma_f32_16x16x32_bf16(af[mi], bfv[ni], acc[mi][ni], 0, 0, 0);
  }
#pragma unroll
  for (int mi = 0; mi < 2; ++mi)
#pragma unroll
    for (int ni = 0; ni < 4; ++ni)
#pragma unroll
      for (int r = 0; r < 4; ++r)
        Amat[(size_t)b * 1048576 + (size_t)(e0 + mi * 16 + lk * 4 + r) * 1024 + h * 64 + ni * 16 + lr]
            = f2bf(acc[mi][ni][r]);
}

// ---------------- launch ----------------
extern "C" void kernel_launch(void* const* d_in, const int* in_sizes, int n_in,
                              void* d_out, int out_size, void* d_ws, size_t ws_size,
                              hipStream_t stream) {
  const float* x    = (const float*)d_in[0];   // [4,2048,1024]
  const float* wqkv = (const float*)d_in[1];   // [3072,1024]
  const float* wo   = (const float*)d_in[2];   // [1024,1024]
  float* out = (float*)d_out;                  // [4,2048,1024] fp32

  char* ws = (char*)d_ws;
  const size_t MB = 1048576;
  unsigned short* xb   = (unsigned short*)(ws + 0);        // 16MB [8192][1024]
  unsigned short* xT   = (unsigned short*)(ws + 16 * MB);  // 16MB [1024][8192]
  unsigned short* wqt  = (unsigned short*)(ws + 32 * MB);  // 2MB
  unsigned short* wk   = (unsigned short*)(ws + 34 * MB);  // 2MB
  unsigned short* wv   = (unsigned short*)(ws + 36 * MB);  // 2MB
  unsigned short* wob  = (unsigned short*)(ws + 38 * MB);  // 2MB
  unsigned short* Gp   = (unsigned short*)(ws + 40 * MB);  // 32MB [4b][4p][1024][1024] (lower tiles)
  unsigned short* G    = (unsigned short*)(ws + 72 * MB);  // 8MB  [4b][1024][1024]  -> peak 80MB
  // reuse dead regions:
  unsigned short* T1p  = (unsigned short*)(ws + 40 * MB);  // 16MB [4b][2p][1024][1024] (over dead Gp)
  float*          Mp   = (float*)        (ws + 56 * MB);   // 4MB  [64 bh][4 ep][64][64] f32
  unsigned short* Amat = (unsigned short*)(ws + 61 * MB);  // 8MB  [4b][1024 e][1024 i]
  unsigned short* Weff = (unsigned short*)(ws + 40 * MB);  // 8MB  (over dead T1p)

  const long M1 = 1048576;

  // all converts in one launch
  prep<<<5376, 256, 0, stream>>>(x, wqkv, wo, xb, xT, wqt, wk, wv, wob);

  // G_b = x_b^T x_b : lower triangle, split-K x4 (576 blocks)
  gemm_tri<<<dim3(36, 1, 16), 256, 0, stream>>>(xT, Gp);
  mirror_reduce<<<dim3(36, 4), 256, 0, stream>>>(Gp, G);

  // T1_b = wk @ G_b (G symmetric), split-K x2 (512 blocks); partials summed in mt_partial
  gemm_bt<false><<<dim3(8, 8, 8), 256, 0, stream>>>(wk, 1024, 0, 512,
                                                    G, 1024, M1, 512,
                                                    (void*)T1p, 1024, 2 * M1, M1, 512, 2);

  // M partials: 256 blocks, f32 out
  mt_partial<<<dim3(64, 4), 256, 0, stream>>>(T1p, wv, Mp);

  // fused: reduce Mp -> Mt -> Amat_b = Wq^T * blockdiag(SCALE*M_b)   (512 blocks)
  amat_fused<<<dim3(8, 64), 256, 0, stream>>>(Mp, wqt, Amat);

  // Weff_b[j][e] = sum_i wo[j][i] * Amat_b[e][i]   (256 blocks)
  gemm_bt<false><<<dim3(8, 8, 4), 256, 0, stream>>>(wob, 1024, 0, 0,
                                                    Amat, 1024, M1, 0,
                                                    (void*)Weff, 1024, M1, 0, 1024, 1);

  // out_b = x_b @ Weff_b^T  (fp32 out)
  gemm_bt<true><<<dim3(8, 16, 4), 256, 0, stream>>>(xb, 1024, 2048 * 1024L, 0,
                                                    Weff, 1024, M1, 0,
                                                    (void*)out, 1024, 2048 * 1024L, 0, 1024, 1);
}

// Round 6
// 158.559 us; speedup vs baseline: 1.4250x; 1.0636x over previous
//
#include <hip/hip_runtime.h>
#include <hip/hip_bf16.h>
#include <cstdint>

// B=4, S=2048, E=1024, H=16, D=64, SCALE = 1/8
#define SCALE_F 0.125f

typedef __attribute__((ext_vector_type(8))) short bf16x8;
typedef __attribute__((ext_vector_type(4))) float f32x4;
typedef __attribute__((ext_vector_type(4))) unsigned short u16x4;
typedef __attribute__((ext_vector_type(8))) unsigned short u16x8;

typedef const __attribute__((address_space(1))) void glb_void;
typedef __attribute__((address_space(3))) void lds_void;

static __device__ __forceinline__ unsigned short f2bf(float f) {
  unsigned u = __builtin_bit_cast(unsigned, f);
  u = (u + 0x7fffu + ((u >> 16) & 1u)) >> 16;
  return (unsigned short)u;
}
static __device__ __forceinline__ float bf2f(unsigned short s) {
  unsigned u = ((unsigned)s) << 16;
  return __builtin_bit_cast(float, u);
}

// chunked XCD swizzle: HW round-robins bid%8 across XCDs; give each XCD a
// contiguous work chunk so co-XCD blocks share operand panels in its L2.
// Bijective when gridDim.x % 8 == 0 (all our GEMM grids are).
static __device__ __forceinline__ int xcd_work(int bid, int nwg) {
  int cpx = nwg >> 3;
  return (bid & 7) * cpx + (bid >> 3);
}

// ---------------- fused prep: all converts in ONE kernel ----------------
__global__ __launch_bounds__(256) void prep(const float* __restrict__ x,
                                            const float* __restrict__ wqkv,
                                            const float* __restrict__ wo,
                                            unsigned short* __restrict__ xb,
                                            unsigned short* __restrict__ xT,
                                            unsigned short* __restrict__ wqt,
                                            unsigned short* __restrict__ wk,
                                            unsigned short* __restrict__ wv,
                                            unsigned short* __restrict__ wob) {
  __shared__ unsigned short lds[64][72];
  const int t = threadIdx.x;
  const int bid = blockIdx.x;

  if (bid < 2048) {
    // ---- cvt_x: x[8192][1024] -> xb + xT ----
    const int r0 = (bid & 127) * 64, c0 = (bid >> 7) * 64;
#pragma unroll
    for (int pass = 0; pass < 4; ++pass) {
      int r = pass * 16 + (t >> 4);
      int c = (t & 15) * 4;
      float4 v = *(const float4*)(x + (size_t)(r0 + r) * 1024 + c0 + c);
      u16x4 o = { f2bf(v.x), f2bf(v.y), f2bf(v.z), f2bf(v.w) };
      *(u16x4*)(xb + (size_t)(r0 + r) * 1024 + c0 + c) = o;
#pragma unroll
      for (int j = 0; j < 4; ++j) {
        int C = c + j;
        lds[C][r ^ ((C & 7) << 3)] = o[j];
      }
    }
    __syncthreads();
#pragma unroll
    for (int pass = 0; pass < 2; ++pass) {
      int rr = pass * 32 + (t >> 3);
      int cc = (t & 7) * 8;
      u16x8 v = *(const u16x8*)&lds[rr][cc ^ ((rr & 7) << 3)];
      *(u16x8*)(xT + (size_t)(c0 + rr) * 8192 + r0 + cc) = v;
    }
  } else if (bid < 5120) {
    // ---- cvt_w: row gathers ----
    int row = bid - 2048;            // 0..3071
    const float* src;
    unsigned short* dst;
    if (row < 1024) {
      int h = row >> 6, k = row & 63;
      src = wqkv + (size_t)(h * 192 + 64 + k) * 1024;
      dst = wk + (size_t)row * 1024;
    } else if (row < 2048) {
      int local = row - 1024;
      int h = local >> 6, k = local & 63;
      src = wqkv + (size_t)(h * 192 + 128 + k) * 1024;
      dst = wv + (size_t)local * 1024;
    } else {
      int local = row - 2048;
      src = wo + (size_t)local * 1024;
      dst = wob + (size_t)local * 1024;
    }
    float4 v = *(const float4*)(src + t * 4);
    u16x4 o = { f2bf(v.x), f2bf(v.y), f2bf(v.z), f2bf(v.w) };
    *(u16x4*)(dst + t * 4) = o;
  } else {
    // ---- wqt transpose: wqt[e][h*64+k] = bf16(wqkv[h*192+k][e]) ----
    int tid = bid - 5120;            // 0..255
    const int r0 = (tid & 15) * 64, c0 = (tid >> 4) * 64;
#pragma unroll
    for (int pass = 0; pass < 4; ++pass) {
      int r = pass * 16 + (t >> 4);
      int c = (t & 15) * 4;
      int gr = r0 + r;
      int srcRow = (gr >> 6) * 192 + (gr & 63);
      float4 v = *(const float4*)(wqkv + (size_t)srcRow * 1024 + c0 + c);
      lds[c + 0][r] = f2bf(v.x);
      lds[c + 1][r] = f2bf(v.y);
      lds[c + 2][r] = f2bf(v.z);
      lds[c + 3][r] = f2bf(v.w);
    }
    __syncthreads();
#pragma unroll
    for (int pass = 0; pass < 2; ++pass) {
      int rr = pass * 32 + (t >> 3);
      int cc = (t & 7) * 8;
      *(u16x8*)(wqt + (size_t)(c0 + rr) * 1024 + r0 + cc) = *(const u16x8*)&lds[rr][cc];
    }
  }
}

// ---------------- generic m97-style bt GEMM, flat grid + XCD swizzle ----------------
// work -> (nx-tile, ny-tile, z); z -> (bb = z/psplit, pp = z%psplit)
template<bool F32OUT>
__global__ __launch_bounds__(256) void gemm_bt(const unsigned short* __restrict__ A, int lda,
                                               long aB, long aP,
                                               const unsigned short* __restrict__ Bm, int ldb,
                                               long bB, long bP,
                                               void* __restrict__ Cv, int ldc,
                                               long cB, long cP,
                                               int K, int psplit, int nx, int ny) {
  __shared__ __align__(16) unsigned short Ash[128 * 32];
  __shared__ __align__(16) unsigned short Bsh[128 * 32];
  const int work = xcd_work(blockIdx.x, gridDim.x);
  const int xt = work % nx;
  const int yt = (work / nx) % ny;
  const int z  = work / (nx * ny);
  const int bb = z / psplit, pp = z % psplit;
  A  += (size_t)bb * aB + (size_t)pp * aP;
  Bm += (size_t)bb * bB + (size_t)pp * bP;
  const int t = threadIdx.x;
  const int w = t >> 6, l = t & 63;
  const int lr = l & 15, lk = l >> 4;
  const int m0 = yt * 128, n0 = xt * 128;
  const int wr = (w >> 1) * 64, wc = (w & 1) * 64;
  f32x4 acc[4][4] = {};

  for (int k0 = 0; k0 < K; k0 += 32) {
#pragma unroll
    for (int i = 0; i < 2; ++i) {
      const int c = i * 256 + t;
      const int row = c >> 2, kc = (c & 3) << 3;
      __builtin_amdgcn_global_load_lds(
          (glb_void*)(A + (size_t)(m0 + row) * lda + k0 + kc),
          (lds_void*)(Ash + i * 2048 + w * 512), 16, 0, 0);
      __builtin_amdgcn_global_load_lds(
          (glb_void*)(Bm + (size_t)(n0 + row) * ldb + k0 + kc),
          (lds_void*)(Bsh + i * 2048 + w * 512), 16, 0, 0);
    }
    __syncthreads();

    bf16x8 af[4], bfv[4];
#pragma unroll
    for (int mi = 0; mi < 4; ++mi)
      af[mi] = *(const bf16x8*)(Ash + (wr + mi * 16 + lr) * 32 + lk * 8);
#pragma unroll
    for (int ni = 0; ni < 4; ++ni)
      bfv[ni] = *(const bf16x8*)(Bsh + (wc + ni * 16 + lr) * 32 + lk * 8);
#pragma unroll
    for (int mi = 0; mi < 4; ++mi)
#pragma unroll
      for (int ni = 0; ni < 4; ++ni)
        acc[mi][ni] = __builtin_amdgcn_mfma_f32_16x16x32_bf16(af[mi], bfv[ni], acc[mi][ni], 0, 0, 0);
    __syncthreads();
  }

#pragma unroll
  for (int mi = 0; mi < 4; ++mi)
#pragma unroll
    for (int ni = 0; ni < 4; ++ni)
#pragma unroll
      for (int r = 0; r < 4; ++r) {
        const size_t row = (size_t)(m0 + wr + mi * 16 + lk * 4 + r);
        const size_t col = (size_t)(n0 + wc + ni * 16 + lr);
        if constexpr (F32OUT)
          ((float*)Cv)[(size_t)bb * cB + (size_t)pp * cP + row * ldc + col] = acc[mi][ni][r];
        else
          ((unsigned short*)Cv)[(size_t)bb * cB + (size_t)pp * cP + row * ldc + col] = f2bf(acc[mi][ni][r]);
      }
}

// ---------------- triangular Gram GEMM, flat grid + XCD swizzle ----------------
// work -> (ti in [0,36) lower-triangle tile, z = b*4+p), K=512
__global__ __launch_bounds__(256) void gemm_tri(const unsigned short* __restrict__ xT,
                                                unsigned short* __restrict__ Gp) {
  __shared__ __align__(16) unsigned short Ash[128 * 32];
  __shared__ __align__(16) unsigned short Bsh[128 * 32];
  const int work = xcd_work(blockIdx.x, gridDim.x);
  int ti = work % 36;
  const int z = work / 36;
  int mt = 0, accum = 0;
  while (accum + mt + 1 <= ti) { accum += mt + 1; ++mt; }
  int nt = ti - accum;
  const int b = z >> 2, p = z & 3;
  const unsigned short* base = xT + (size_t)b * 2048 + (size_t)p * 512;

  const int t = threadIdx.x;
  const int w = t >> 6, l = t & 63;
  const int lr = l & 15, lk = l >> 4;
  const int m0 = mt * 128, n0 = nt * 128;
  const int wr = (w >> 1) * 64, wc = (w & 1) * 64;
  f32x4 acc[4][4] = {};

  for (int k0 = 0; k0 < 512; k0 += 32) {
#pragma unroll
    for (int i = 0; i < 2; ++i) {
      const int c = i * 256 + t;
      const int row = c >> 2, kc = (c & 3) << 3;
      __builtin_amdgcn_global_load_lds(
          (glb_void*)(base + (size_t)(m0 + row) * 8192 + k0 + kc),
          (lds_void*)(Ash + i * 2048 + w * 512), 16, 0, 0);
      __builtin_amdgcn_global_load_lds(
          (glb_void*)(base + (size_t)(n0 + row) * 8192 + k0 + kc),
          (lds_void*)(Bsh + i * 2048 + w * 512), 16, 0, 0);
    }
    __syncthreads();

    bf16x8 af[4], bfv[4];
#pragma unroll
    for (int mi = 0; mi < 4; ++mi)
      af[mi] = *(const bf16x8*)(Ash + (wr + mi * 16 + lr) * 32 + lk * 8);
#pragma unroll
    for (int ni = 0; ni < 4; ++ni)
      bfv[ni] = *(const bf16x8*)(Bsh + (wc + ni * 16 + lr) * 32 + lk * 8);
#pragma unroll
    for (int mi = 0; mi < 4; ++mi)
#pragma unroll
      for (int ni = 0; ni < 4; ++ni)
        acc[mi][ni] = __builtin_amdgcn_mfma_f32_16x16x32_bf16(af[mi], bfv[ni], acc[mi][ni], 0, 0, 0);
    __syncthreads();
  }

  unsigned short* out = Gp + (size_t)z * 1048576;
#pragma unroll
  for (int mi = 0; mi < 4; ++mi)
#pragma unroll
    for (int ni = 0; ni < 4; ++ni)
#pragma unroll
      for (int r = 0; r < 4; ++r)
        out[(size_t)(m0 + wr + mi * 16 + lk * 4 + r) * 1024 + n0 + wc + ni * 16 + lr]
            = f2bf(acc[mi][ni][r]);
}

// ---------------- mirror+reduce via LDS transpose ----------------
__global__ __launch_bounds__(256) void mirror_reduce(const unsigned short* __restrict__ Gp,
                                                     unsigned short* __restrict__ G) {
  __shared__ unsigned short ldsT[128][128];
  int ti = blockIdx.x;
  int mt = 0, accum = 0;
  while (accum + mt + 1 <= ti) { accum += mt + 1; ++mt; }
  int nt = ti - accum;
  const int b = blockIdx.y;
  const int m0 = mt * 128, n0 = nt * 128;
  const unsigned short* base = Gp + (size_t)b * 4 * 1048576;
  unsigned short* Gb = G + (size_t)b * 1048576;
  const int t = threadIdx.x;

#pragma unroll
  for (int pass = 0; pass < 8; ++pass) {
    int idx = pass * 2048 + t * 8;
    int r = idx >> 7, c = idx & 127;
    float s[8] = {};
#pragma unroll
    for (int p = 0; p < 4; ++p) {
      u16x8 v = *(const u16x8*)(base + (size_t)p * 1048576 + (size_t)(m0 + r) * 1024 + n0 + c);
#pragma unroll
      for (int j = 0; j < 8; ++j) s[j] += bf2f(v[j]);
    }
    u16x8 o;
#pragma unroll
    for (int j = 0; j < 8; ++j) o[j] = f2bf(s[j]);
    *(u16x8*)(Gb + (size_t)(m0 + r) * 1024 + n0 + c) = o;
#pragma unroll
    for (int j = 0; j < 8; ++j) {
      int col = c + j;
      ldsT[col][r ^ (((col >> 3) & 7) << 3)] = o[j];
    }
  }

  if (mt != nt) {
    __syncthreads();
#pragma unroll
    for (int pass = 0; pass < 8; ++pass) {
      int idx = pass * 2048 + t * 8;
      int rr = idx >> 7, cc = idx & 127;
      u16x8 v = *(const u16x8*)&ldsT[rr][cc ^ (((rr >> 3) & 7) << 3)];
      *(u16x8*)(Gb + (size_t)(n0 + rr) * 1024 + m0 + cc) = v;
    }
  }
}

// ---------------- Mp[bh][ep][k][d'] partials ----------------
__global__ __launch_bounds__(256) void mt_partial(const unsigned short* __restrict__ T1p,
                                                  const unsigned short* __restrict__ wv,
                                                  float* __restrict__ Mp) {
  __shared__ float Msh[4096];   // [k][d'] linear
  const int t = threadIdx.x;
  const int w = t >> 6, l = t & 63;
  const int lr = l & 15, lk = l >> 4;
  const int bh = blockIdx.x, ep = blockIdx.y;
  const int b = bh >> 4, h = bh & 15;
  const int p = w >> 1, half = w & 1;

  for (int i = t; i < 4096; i += 256) Msh[i] = 0.f;
  __syncthreads();

  const unsigned short* Ab = T1p + (size_t)(b * 2 + p) * 1048576 + (size_t)(h * 64) * 1024;
  const unsigned short* Bb = wv + (size_t)(h * 64) * 1024;
  f32x4 acc[4][4] = {};
  const int ebeg = ep * 256 + half * 128;
#pragma unroll
  for (int e0 = ebeg; e0 < ebeg + 128; e0 += 32) {
    bf16x8 af[4], bfv[4];
#pragma unroll
    for (int mi = 0; mi < 4; ++mi)
      af[mi] = *(const bf16x8*)(Ab + (size_t)(mi * 16 + lr) * 1024 + e0 + lk * 8);
#pragma unroll
    for (int ni = 0; ni < 4; ++ni)
      bfv[ni] = *(const bf16x8*)(Bb + (size_t)(ni * 16 + lr) * 1024 + e0 + lk * 8);
#pragma unroll
    for (int mi = 0; mi < 4; ++mi)
#pragma unroll
      for (int ni = 0; ni < 4; ++ni)
        acc[mi][ni] = __builtin_amdgcn_mfma_f32_16x16x32_bf16(af[mi], bfv[ni], acc[mi][ni], 0, 0, 0);
  }
#pragma unroll
  for (int mi = 0; mi < 4; ++mi)
#pragma unroll
    for (int ni = 0; ni < 4; ++ni)
#pragma unroll
      for (int r = 0; r < 4; ++r)
        atomicAdd(&Msh[(mi * 16 + lk * 4 + r) * 64 + ni * 16 + lr], acc[mi][ni][r]);
  __syncthreads();

  float* out = Mp + ((size_t)bh * 4 + ep) * 4096;
  for (int i = t * 4; i < 4096; i += 1024)
    *(float4*)(out + i) = *(const float4*)&Msh[i];
}

// ---------------- fused: reduce Mp -> Mt (LDS) -> Amat slice ----------------
__global__ __launch_bounds__(256) void amat_fused(const float* __restrict__ Mp,
                                                  const unsigned short* __restrict__ wqt,
                                                  unsigned short* __restrict__ Amat) {
  __shared__ float Msh[64 * 68];            // [k][dp], padded row 68
  __shared__ unsigned short MtSh[64][80];   // [dp][k], padded row 80
  const int t = threadIdx.x;
  const int et = blockIdx.x, bh = blockIdx.y;
  const int b = bh >> 4, h = bh & 15;

  const float* base = Mp + (size_t)bh * 16384;
  for (int i = t * 4; i < 4096; i += 1024) {
    float4 s = *(const float4*)(base + i);
#pragma unroll
    for (int p = 1; p < 4; ++p) {
      float4 v = *(const float4*)(base + p * 4096 + i);
      s.x += v.x; s.y += v.y; s.z += v.z; s.w += v.w;
    }
    int k = i >> 6, dp = i & 63;
    *(float4*)&Msh[k * 68 + dp] = s;
  }
  __syncthreads();

  for (int i = t; i < 4096; i += 256) {
    int dp = i >> 6, k = i & 63;
    MtSh[dp][k] = f2bf(Msh[k * 68 + dp] * SCALE_F);
  }
  __syncthreads();

  const int w = t >> 6, l = t & 63;
  const int lr = l & 15, lk = l >> 4;
  const int e0 = et * 128 + w * 32;

  f32x4 acc[2][4] = {};
#pragma unroll
  for (int ks = 0; ks < 2; ++ks) {
    bf16x8 af[2], bfv[4];
#pragma unroll
    for (int mi = 0; mi < 2; ++mi)
      af[mi] = *(const bf16x8*)(wqt + (size_t)(e0 + mi * 16 + lr) * 1024 + h * 64 + ks * 32 + lk * 8);
#pragma unroll
    for (int ni = 0; ni < 4; ++ni)
      bfv[ni] = *(const bf16x8*)(&MtSh[ni * 16 + lr][ks * 32 + lk * 8]);
#pragma unroll
    for (int mi = 0; mi < 2; ++mi)
#pragma unroll
      for (int ni = 0; ni < 4; ++ni)
        acc[mi][ni] = __builtin_amdgcn_mfma_f32_16x16x32_bf16(af[mi], bfv[ni], acc[mi][ni], 0, 0, 0);
  }
#pragma unroll
  for (int mi = 0; mi < 2; ++mi)
#pragma unroll
    for (int ni = 0; ni < 4; ++ni)
#pragma unroll
      for (int r = 0; r < 4; ++r)
        Amat[(size_t)b * 1048576 + (size_t)(e0 + mi * 16 + lk * 4 + r) * 1024 + h * 64 + ni * 16 + lr]
            = f2bf(acc[mi][ni][r]);
}

// ---------------- launch ----------------
extern "C" void kernel_launch(void* const* d_in, const int* in_sizes, int n_in,
                              void* d_out, int out_size, void* d_ws, size_t ws_size,
                              hipStream_t stream) {
  const float* x    = (const float*)d_in[0];   // [4,2048,1024]
  const float* wqkv = (const float*)d_in[1];   // [3072,1024]
  const float* wo   = (const float*)d_in[2];   // [1024,1024]
  float* out = (float*)d_out;                  // [4,2048,1024] fp32

  char* ws = (char*)d_ws;
  const size_t MB = 1048576;
  unsigned short* xb   = (unsigned short*)(ws + 0);        // 16MB [8192][1024]
  unsigned short* xT   = (unsigned short*)(ws + 16 * MB);  // 16MB [1024][8192]
  unsigned short* wqt  = (unsigned short*)(ws + 32 * MB);  // 2MB
  unsigned short* wk   = (unsigned short*)(ws + 34 * MB);  // 2MB
  unsigned short* wv   = (unsigned short*)(ws + 36 * MB);  // 2MB
  unsigned short* wob  = (unsigned short*)(ws + 38 * MB);  // 2MB
  unsigned short* Gp   = (unsigned short*)(ws + 40 * MB);  // 32MB [4b][4p][1024][1024] (lower tiles)
  unsigned short* G    = (unsigned short*)(ws + 72 * MB);  // 8MB  [4b][1024][1024]  -> peak 80MB
  // reuse dead regions:
  unsigned short* T1p  = (unsigned short*)(ws + 40 * MB);  // 16MB [4b][2p][1024][1024] (over dead Gp)
  float*          Mp   = (float*)        (ws + 56 * MB);   // 4MB  [64 bh][4 ep][64][64] f32
  unsigned short* Amat = (unsigned short*)(ws + 61 * MB);  // 8MB  [4b][1024 e][1024 i]
  unsigned short* Weff = (unsigned short*)(ws + 40 * MB);  // 8MB  (over dead T1p)

  const long M1 = 1048576;

  // all converts in one launch
  prep<<<5376, 256, 0, stream>>>(x, wqkv, wo, xb, xT, wqt, wk, wv, wob);

  // G_b = x_b^T x_b : lower triangle, split-K x4 (576 blocks, swizzled)
  gemm_tri<<<576, 256, 0, stream>>>(xT, Gp);
  mirror_reduce<<<dim3(36, 4), 256, 0, stream>>>(Gp, G);

  // T1_b = wk @ G_b (G symmetric), split-K x2 (512 blocks, swizzled)
  gemm_bt<false><<<512, 256, 0, stream>>>(wk, 1024, 0, 512,
                                          G, 1024, M1, 512,
                                          (void*)T1p, 1024, 2 * M1, M1, 512, 2, 8, 8);

  // M partials: 256 blocks, f32 out
  mt_partial<<<dim3(64, 4), 256, 0, stream>>>(T1p, wv, Mp);

  // fused: reduce Mp -> Mt -> Amat_b = Wq^T * blockdiag(SCALE*M_b)   (512 blocks)
  amat_fused<<<dim3(8, 64), 256, 0, stream>>>(Mp, wqt, Amat);

  // Weff_b[j][e] = sum_i wo[j][i] * Amat_b[e][i]   (256 blocks, swizzled)
  gemm_bt<false><<<256, 256, 0, stream>>>(wob, 1024, 0, 0,
                                          Amat, 1024, M1, 0,
                                          (void*)Weff, 1024, M1, 0, 1024, 1, 8, 8);

  // out_b = x_b @ Weff_b^T  (fp32 out; 512 blocks, swizzled; chunk=64 covers 8x8 tile square)
  gemm_bt<true><<<512, 256, 0, stream>>>(xb, 1024, 2048 * 1024L, 0,
                                         Weff, 1024, M1, 0,
                                         (void*)out, 1024, 2048 * 1024L, 0, 1024, 1, 8, 16);
}

// Round 7
// 151.350 us; speedup vs baseline: 1.4929x; 1.0476x over previous
//
#include <hip/hip_runtime.h>
#include <hip/hip_bf16.h>
#include <cstdint>

// B=4, S=2048, E=1024, H=16, D=64, SCALE = 1/8
#define SCALE_F 0.125f

typedef __attribute__((ext_vector_type(8))) short bf16x8;
typedef __attribute__((ext_vector_type(4))) float f32x4;
typedef __attribute__((ext_vector_type(4))) unsigned short u16x4;
typedef __attribute__((ext_vector_type(8))) unsigned short u16x8;

typedef const __attribute__((address_space(1))) void glb_void;
typedef __attribute__((address_space(3))) void lds_void;

static __device__ __forceinline__ unsigned short f2bf(float f) {
  unsigned u = __builtin_bit_cast(unsigned, f);
  u = (u + 0x7fffu + ((u >> 16) & 1u)) >> 16;
  return (unsigned short)u;
}
static __device__ __forceinline__ float bf2f(unsigned short s) {
  unsigned u = ((unsigned)s) << 16;
  return __builtin_bit_cast(float, u);
}

// chunked XCD swizzle (bijective: all our grids are multiples of 8)
static __device__ __forceinline__ int xcd_work(int bid, int nwg) {
  int cpx = nwg >> 3;
  return (bid & 7) * cpx + (bid >> 3);
}

// ---------------- fused prep: all converts in ONE kernel ----------------
__global__ __launch_bounds__(256) void prep(const float* __restrict__ x,
                                            const float* __restrict__ wqkv,
                                            const float* __restrict__ wo,
                                            unsigned short* __restrict__ xb,
                                            unsigned short* __restrict__ xT,
                                            unsigned short* __restrict__ wqt,
                                            unsigned short* __restrict__ wk,
                                            unsigned short* __restrict__ wv,
                                            unsigned short* __restrict__ wob) {
  __shared__ unsigned short lds[64][72];
  const int t = threadIdx.x;
  const int bid = blockIdx.x;

  if (bid < 2048) {
    // ---- cvt_x: x[8192][1024] -> xb + xT ----
    const int r0 = (bid & 127) * 64, c0 = (bid >> 7) * 64;
#pragma unroll
    for (int pass = 0; pass < 4; ++pass) {
      int r = pass * 16 + (t >> 4);
      int c = (t & 15) * 4;
      float4 v = *(const float4*)(x + (size_t)(r0 + r) * 1024 + c0 + c);
      u16x4 o = { f2bf(v.x), f2bf(v.y), f2bf(v.z), f2bf(v.w) };
      *(u16x4*)(xb + (size_t)(r0 + r) * 1024 + c0 + c) = o;
#pragma unroll
      for (int j = 0; j < 4; ++j) {
        int C = c + j;
        lds[C][r ^ ((C & 7) << 3)] = o[j];
      }
    }
    __syncthreads();
#pragma unroll
    for (int pass = 0; pass < 2; ++pass) {
      int rr = pass * 32 + (t >> 3);
      int cc = (t & 7) * 8;
      u16x8 v = *(const u16x8*)&lds[rr][cc ^ ((rr & 7) << 3)];
      *(u16x8*)(xT + (size_t)(c0 + rr) * 8192 + r0 + cc) = v;
    }
  } else if (bid < 5120) {
    // ---- cvt_w: row gathers ----
    int row = bid - 2048;            // 0..3071
    const float* src;
    unsigned short* dst;
    if (row < 1024) {
      int h = row >> 6, k = row & 63;
      src = wqkv + (size_t)(h * 192 + 64 + k) * 1024;
      dst = wk + (size_t)row * 1024;
    } else if (row < 2048) {
      int local = row - 1024;
      int h = local >> 6, k = local & 63;
      src = wqkv + (size_t)(h * 192 + 128 + k) * 1024;
      dst = wv + (size_t)local * 1024;
    } else {
      int local = row - 2048;
      src = wo + (size_t)local * 1024;
      dst = wob + (size_t)local * 1024;
    }
    float4 v = *(const float4*)(src + t * 4);
    u16x4 o = { f2bf(v.x), f2bf(v.y), f2bf(v.z), f2bf(v.w) };
    *(u16x4*)(dst + t * 4) = o;
  } else {
    // ---- wqt transpose: wqt[e][h*64+k] = bf16(wqkv[h*192+k][e]) ----
    int tid = bid - 5120;            // 0..255
    const int r0 = (tid & 15) * 64, c0 = (tid >> 4) * 64;
#pragma unroll
    for (int pass = 0; pass < 4; ++pass) {
      int r = pass * 16 + (t >> 4);
      int c = (t & 15) * 4;
      int gr = r0 + r;
      int srcRow = (gr >> 6) * 192 + (gr & 63);
      float4 v = *(const float4*)(wqkv + (size_t)srcRow * 1024 + c0 + c);
      lds[c + 0][r] = f2bf(v.x);
      lds[c + 1][r] = f2bf(v.y);
      lds[c + 2][r] = f2bf(v.z);
      lds[c + 3][r] = f2bf(v.w);
    }
    __syncthreads();
#pragma unroll
    for (int pass = 0; pass < 2; ++pass) {
      int rr = pass * 32 + (t >> 3);
      int cc = (t & 7) * 8;
      *(u16x8*)(wqt + (size_t)(c0 + rr) * 1024 + r0 + cc) = *(const u16x8*)&lds[rr][cc];
    }
  }
}

// ---------------- m97-style bt GEMM, 8 waves/block, flat grid + XCD swizzle ----------------
// wave w owns 64x32 sub-tile: wr=(w>>2)*64, wc=(w&3)*32; acc[4][2]
template<bool F32OUT>
__global__ __launch_bounds__(512) void gemm_bt(const unsigned short* __restrict__ A, int lda,
                                               long aB, long aP,
                                               const unsigned short* __restrict__ Bm, int ldb,
                                               long bB, long bP,
                                               void* __restrict__ Cv, int ldc,
                                               long cB, long cP,
                                               int K, int psplit, int nx, int ny) {
  __shared__ __align__(16) unsigned short Ash[128 * 32];
  __shared__ __align__(16) unsigned short Bsh[128 * 32];
  const int work = xcd_work(blockIdx.x, gridDim.x);
  const int xt = work % nx;
  const int yt = (work / nx) % ny;
  const int z  = work / (nx * ny);
  const int bb = z / psplit, pp = z % psplit;
  A  += (size_t)bb * aB + (size_t)pp * aP;
  Bm += (size_t)bb * bB + (size_t)pp * bP;
  const int t = threadIdx.x;
  const int w = t >> 6, l = t & 63;
  const int lr = l & 15, lk = l >> 4;
  const int m0 = yt * 128, n0 = xt * 128;
  const int wr = (w >> 2) * 64, wc = (w & 3) * 32;
  const int srow = t >> 2, skc = (t & 3) << 3;   // staging: 1 load/thread/operand
  f32x4 acc[4][2] = {};

  for (int k0 = 0; k0 < K; k0 += 32) {
    __builtin_amdgcn_global_load_lds(
        (glb_void*)(A + (size_t)(m0 + srow) * lda + k0 + skc),
        (lds_void*)(Ash + w * 512), 16, 0, 0);
    __builtin_amdgcn_global_load_lds(
        (glb_void*)(Bm + (size_t)(n0 + srow) * ldb + k0 + skc),
        (lds_void*)(Bsh + w * 512), 16, 0, 0);
    __syncthreads();

    bf16x8 af[4], bfv[2];
#pragma unroll
    for (int mi = 0; mi < 4; ++mi)
      af[mi] = *(const bf16x8*)(Ash + (wr + mi * 16 + lr) * 32 + lk * 8);
#pragma unroll
    for (int ni = 0; ni < 2; ++ni)
      bfv[ni] = *(const bf16x8*)(Bsh + (wc + ni * 16 + lr) * 32 + lk * 8);
#pragma unroll
    for (int mi = 0; mi < 4; ++mi)
#pragma unroll
      for (int ni = 0; ni < 2; ++ni)
        acc[mi][ni] = __builtin_amdgcn_mfma_f32_16x16x32_bf16(af[mi], bfv[ni], acc[mi][ni], 0, 0, 0);
    __syncthreads();
  }

#pragma unroll
  for (int mi = 0; mi < 4; ++mi)
#pragma unroll
    for (int ni = 0; ni < 2; ++ni)
#pragma unroll
      for (int r = 0; r < 4; ++r) {
        const size_t row = (size_t)(m0 + wr + mi * 16 + lk * 4 + r);
        const size_t col = (size_t)(n0 + wc + ni * 16 + lr);
        if constexpr (F32OUT)
          ((float*)Cv)[(size_t)bb * cB + (size_t)pp * cP + row * ldc + col] = acc[mi][ni][r];
        else
          ((unsigned short*)Cv)[(size_t)bb * cB + (size_t)pp * cP + row * ldc + col] = f2bf(acc[mi][ni][r]);
      }
}

// ---------------- triangular Gram GEMM, 8 waves/block, XCD swizzle ----------------
__global__ __launch_bounds__(512) void gemm_tri(const unsigned short* __restrict__ xT,
                                                unsigned short* __restrict__ Gp) {
  __shared__ __align__(16) unsigned short Ash[128 * 32];
  __shared__ __align__(16) unsigned short Bsh[128 * 32];
  const int work = xcd_work(blockIdx.x, gridDim.x);
  int ti = work % 36;
  const int z = work / 36;
  int mt = 0, accum = 0;
  while (accum + mt + 1 <= ti) { accum += mt + 1; ++mt; }
  int nt = ti - accum;
  const int b = z >> 2, p = z & 3;
  const unsigned short* base = xT + (size_t)b * 2048 + (size_t)p * 512;

  const int t = threadIdx.x;
  const int w = t >> 6, l = t & 63;
  const int lr = l & 15, lk = l >> 4;
  const int m0 = mt * 128, n0 = nt * 128;
  const int wr = (w >> 2) * 64, wc = (w & 3) * 32;
  const int srow = t >> 2, skc = (t & 3) << 3;
  f32x4 acc[4][2] = {};

  for (int k0 = 0; k0 < 512; k0 += 32) {
    __builtin_amdgcn_global_load_lds(
        (glb_void*)(base + (size_t)(m0 + srow) * 8192 + k0 + skc),
        (lds_void*)(Ash + w * 512), 16, 0, 0);
    __builtin_amdgcn_global_load_lds(
        (glb_void*)(base + (size_t)(n0 + srow) * 8192 + k0 + skc),
        (lds_void*)(Bsh + w * 512), 16, 0, 0);
    __syncthreads();

    bf16x8 af[4], bfv[2];
#pragma unroll
    for (int mi = 0; mi < 4; ++mi)
      af[mi] = *(const bf16x8*)(Ash + (wr + mi * 16 + lr) * 32 + lk * 8);
#pragma unroll
    for (int ni = 0; ni < 2; ++ni)
      bfv[ni] = *(const bf16x8*)(Bsh + (wc + ni * 16 + lr) * 32 + lk * 8);
#pragma unroll
    for (int mi = 0; mi < 4; ++mi)
#pragma unroll
      for (int ni = 0; ni < 2; ++ni)
        acc[mi][ni] = __builtin_amdgcn_mfma_f32_16x16x32_bf16(af[mi], bfv[ni], acc[mi][ni], 0, 0, 0);
    __syncthreads();
  }

  unsigned short* out = Gp + (size_t)z * 1048576;
#pragma unroll
  for (int mi = 0; mi < 4; ++mi)
#pragma unroll
    for (int ni = 0; ni < 2; ++ni)
#pragma unroll
      for (int r = 0; r < 4; ++r)
        out[(size_t)(m0 + wr + mi * 16 + lk * 4 + r) * 1024 + n0 + wc + ni * 16 + lr]
            = f2bf(acc[mi][ni][r]);
}

// ---------------- mirror+reduce via LDS transpose ----------------
__global__ __launch_bounds__(256) void mirror_reduce(const unsigned short* __restrict__ Gp,
                                                     unsigned short* __restrict__ G) {
  __shared__ unsigned short ldsT[128][128];
  int ti = blockIdx.x;
  int mt = 0, accum = 0;
  while (accum + mt + 1 <= ti) { accum += mt + 1; ++mt; }
  int nt = ti - accum;
  const int b = blockIdx.y;
  const int m0 = mt * 128, n0 = nt * 128;
  const unsigned short* base = Gp + (size_t)b * 4 * 1048576;
  unsigned short* Gb = G + (size_t)b * 1048576;
  const int t = threadIdx.x;

#pragma unroll
  for (int pass = 0; pass < 8; ++pass) {
    int idx = pass * 2048 + t * 8;
    int r = idx >> 7, c = idx & 127;
    float s[8] = {};
#pragma unroll
    for (int p = 0; p < 4; ++p) {
      u16x8 v = *(const u16x8*)(base + (size_t)p * 1048576 + (size_t)(m0 + r) * 1024 + n0 + c);
#pragma unroll
      for (int j = 0; j < 8; ++j) s[j] += bf2f(v[j]);
    }
    u16x8 o;
#pragma unroll
    for (int j = 0; j < 8; ++j) o[j] = f2bf(s[j]);
    *(u16x8*)(Gb + (size_t)(m0 + r) * 1024 + n0 + c) = o;
#pragma unroll
    for (int j = 0; j < 8; ++j) {
      int col = c + j;
      ldsT[col][r ^ (((col >> 3) & 7) << 3)] = o[j];
    }
  }

  if (mt != nt) {
    __syncthreads();
#pragma unroll
    for (int pass = 0; pass < 8; ++pass) {
      int idx = pass * 2048 + t * 8;
      int rr = idx >> 7, cc = idx & 127;
      u16x8 v = *(const u16x8*)&ldsT[rr][cc ^ (((rr >> 3) & 7) << 3)];
      *(u16x8*)(Gb + (size_t)(n0 + rr) * 1024 + m0 + cc) = v;
    }
  }
}

// ---------------- Mp[bh][ep][k][d'] partials ----------------
__global__ __launch_bounds__(256) void mt_partial(const unsigned short* __restrict__ T1p,
                                                  const unsigned short* __restrict__ wv,
                                                  float* __restrict__ Mp) {
  __shared__ float Msh[4096];   // [k][d'] linear
  const int t = threadIdx.x;
  const int w = t >> 6, l = t & 63;
  const int lr = l & 15, lk = l >> 4;
  const int bh = blockIdx.x, ep = blockIdx.y;
  const int b = bh >> 4, h = bh & 15;
  const int p = w >> 1, half = w & 1;

  for (int i = t; i < 4096; i += 256) Msh[i] = 0.f;
  __syncthreads();

  const unsigned short* Ab = T1p + (size_t)(b * 2 + p) * 1048576 + (size_t)(h * 64) * 1024;
  const unsigned short* Bb = wv + (size_t)(h * 64) * 1024;
  f32x4 acc[4][4] = {};
  const int ebeg = ep * 256 + half * 128;
#pragma unroll
  for (int e0 = ebeg; e0 < ebeg + 128; e0 += 32) {
    bf16x8 af[4], bfv[4];
#pragma unroll
    for (int mi = 0; mi < 4; ++mi)
      af[mi] = *(const bf16x8*)(Ab + (size_t)(mi * 16 + lr) * 1024 + e0 + lk * 8);
#pragma unroll
    for (int ni = 0; ni < 4; ++ni)
      bfv[ni] = *(const bf16x8*)(Bb + (size_t)(ni * 16 + lr) * 1024 + e0 + lk * 8);
#pragma unroll
    for (int mi = 0; mi < 4; ++mi)
#pragma unroll
      for (int ni = 0; ni < 4; ++ni)
        acc[mi][ni] = __builtin_amdgcn_mfma_f32_16x16x32_bf16(af[mi], bfv[ni], acc[mi][ni], 0, 0, 0);
  }
#pragma unroll
  for (int mi = 0; mi < 4; ++mi)
#pragma unroll
    for (int ni = 0; ni < 4; ++ni)
#pragma unroll
      for (int r = 0; r < 4; ++r)
        atomicAdd(&Msh[(mi * 16 + lk * 4 + r) * 64 + ni * 16 + lr], acc[mi][ni][r]);
  __syncthreads();

  float* out = Mp + ((size_t)bh * 4 + ep) * 4096;
  for (int i = t * 4; i < 4096; i += 1024)
    *(float4*)(out + i) = *(const float4*)&Msh[i];
}

// ---------------- fused: reduce Mp -> Mt (LDS) -> Amat slice ----------------
__global__ __launch_bounds__(256) void amat_fused(const float* __restrict__ Mp,
                                                  const unsigned short* __restrict__ wqt,
                                                  unsigned short* __restrict__ Amat) {
  __shared__ float Msh[64 * 68];            // [k][dp], padded row 68
  __shared__ unsigned short MtSh[64][80];   // [dp][k], padded row 80
  const int t = threadIdx.x;
  const int et = blockIdx.x, bh = blockIdx.y;
  const int b = bh >> 4, h = bh & 15;

  const float* base = Mp + (size_t)bh * 16384;
  for (int i = t * 4; i < 4096; i += 1024) {
    float4 s = *(const float4*)(base + i);
#pragma unroll
    for (int p = 1; p < 4; ++p) {
      float4 v = *(const float4*)(base + p * 4096 + i);
      s.x += v.x; s.y += v.y; s.z += v.z; s.w += v.w;
    }
    int k = i >> 6, dp = i & 63;
    *(float4*)&Msh[k * 68 + dp] = s;
  }
  __syncthreads();

  for (int i = t; i < 4096; i += 256) {
    int dp = i >> 6, k = i & 63;
    MtSh[dp][k] = f2bf(Msh[k * 68 + dp] * SCALE_F);
  }
  __syncthreads();

  const int w = t >> 6, l = t & 63;
  const int lr = l & 15, lk = l >> 4;
  const int e0 = et * 128 + w * 32;

  f32x4 acc[2][4] = {};
#pragma unroll
  for (int ks = 0; ks < 2; ++ks) {
    bf16x8 af[2], bfv[4];
#pragma unroll
    for (int mi = 0; mi < 2; ++mi)
      af[mi] = *(const bf16x8*)(wqt + (size_t)(e0 + mi * 16 + lr) * 1024 + h * 64 + ks * 32 + lk * 8);
#pragma unroll
    for (int ni = 0; ni < 4; ++ni)
      bfv[ni] = *(const bf16x8*)(&MtSh[ni * 16 + lr][ks * 32 + lk * 8]);
#pragma unroll
    for (int mi = 0; mi < 2; ++mi)
#pragma unroll
      for (int ni = 0; ni < 4; ++ni)
        acc[mi][ni] = __builtin_amdgcn_mfma_f32_16x16x32_bf16(af[mi], bfv[ni], acc[mi][ni], 0, 0, 0);
  }
#pragma unroll
  for (int mi = 0; mi < 2; ++mi)
#pragma unroll
    for (int ni = 0; ni < 4; ++ni)
#pragma unroll
      for (int r = 0; r < 4; ++r)
        Amat[(size_t)b * 1048576 + (size_t)(e0 + mi * 16 + lk * 4 + r) * 1024 + h * 64 + ni * 16 + lr]
            = f2bf(acc[mi][ni][r]);
}

// ---------------- launch ----------------
extern "C" void kernel_launch(void* const* d_in, const int* in_sizes, int n_in,
                              void* d_out, int out_size, void* d_ws, size_t ws_size,
                              hipStream_t stream) {
  const float* x    = (const float*)d_in[0];   // [4,2048,1024]
  const float* wqkv = (const float*)d_in[1];   // [3072,1024]
  const float* wo   = (const float*)d_in[2];   // [1024,1024]
  float* out = (float*)d_out;                  // [4,2048,1024] fp32

  char* ws = (char*)d_ws;
  const size_t MB = 1048576;
  unsigned short* xb   = (unsigned short*)(ws + 0);        // 16MB [8192][1024]
  unsigned short* xT   = (unsigned short*)(ws + 16 * MB);  // 16MB [1024][8192]
  unsigned short* wqt  = (unsigned short*)(ws + 32 * MB);  // 2MB
  unsigned short* wk   = (unsigned short*)(ws + 34 * MB);  // 2MB
  unsigned short* wv   = (unsigned short*)(ws + 36 * MB);  // 2MB
  unsigned short* wob  = (unsigned short*)(ws + 38 * MB);  // 2MB
  unsigned short* Gp   = (unsigned short*)(ws + 40 * MB);  // 32MB [4b][4p][1024][1024] (lower tiles)
  unsigned short* G    = (unsigned short*)(ws + 72 * MB);  // 8MB  [4b][1024][1024]  -> peak 80MB
  // reuse dead regions:
  unsigned short* T1p  = (unsigned short*)(ws + 40 * MB);  // 16MB [4b][2p][1024][1024] (over dead Gp)
  float*          Mp   = (float*)        (ws + 56 * MB);   // 4MB  [64 bh][4 ep][64][64] f32
  unsigned short* Amat = (unsigned short*)(ws + 61 * MB);  // 8MB  [4b][1024 e][1024 i]
  unsigned short* Weff = (unsigned short*)(ws + 40 * MB);  // 8MB  (over dead T1p)

  const long M1 = 1048576;

  // all converts in one launch
  prep<<<5376, 256, 0, stream>>>(x, wqkv, wo, xb, xT, wqt, wk, wv, wob);

  // G_b = x_b^T x_b : lower triangle, split-K x4 (576 blocks, swizzled, 8 waves)
  gemm_tri<<<576, 512, 0, stream>>>(xT, Gp);
  mirror_reduce<<<dim3(36, 4), 256, 0, stream>>>(Gp, G);

  // T1_b = wk @ G_b (G symmetric), split-K x2 (512 blocks, swizzled, 8 waves)
  gemm_bt<false><<<512, 512, 0, stream>>>(wk, 1024, 0, 512,
                                          G, 1024, M1, 512,
                                          (void*)T1p, 1024, 2 * M1, M1, 512, 2, 8, 8);

  // M partials: 256 blocks, f32 out
  mt_partial<<<dim3(64, 4), 256, 0, stream>>>(T1p, wv, Mp);

  // fused: reduce Mp -> Mt -> Amat_b = Wq^T * blockdiag(SCALE*M_b)   (512 blocks)
  amat_fused<<<dim3(8, 64), 256, 0, stream>>>(Mp, wqt, Amat);

  // Weff_b[j][e] = sum_i wo[j][i] * Amat_b[e][i]   (256 blocks, swizzled, 8 waves)
  gemm_bt<false><<<256, 512, 0, stream>>>(wob, 1024, 0, 0,
                                          Amat, 1024, M1, 0,
                                          (void*)Weff, 1024, M1, 0, 1024, 1, 8, 8);

  // out_b = x_b @ Weff_b^T  (fp32 out; 512 blocks, swizzled, 8 waves)
  gemm_bt<true><<<512, 512, 0, stream>>>(xb, 1024, 2048 * 1024L, 0,
                                         Weff, 1024, M1, 0,
                                         (void*)out, 1024, 2048 * 1024L, 0, 1024, 1, 8, 16);
}

// Round 8
// 145.103 us; speedup vs baseline: 1.5572x; 1.0431x over previous
//
#include <hip/hip_runtime.h>
#include <hip/hip_bf16.h>
#include <cstdint>

// B=4, S=2048, E=1024, H=16, D=64, SCALE = 1/8
#define SCALE_F 0.125f

typedef __attribute__((ext_vector_type(8))) short bf16x8;
typedef __attribute__((ext_vector_type(4))) float f32x4;
typedef __attribute__((ext_vector_type(4))) unsigned short u16x4;
typedef __attribute__((ext_vector_type(8))) unsigned short u16x8;

typedef const __attribute__((address_space(1))) void glb_void;
typedef __attribute__((address_space(3))) void lds_void;

static __device__ __forceinline__ unsigned short f2bf(float f) {
  unsigned u = __builtin_bit_cast(unsigned, f);
  u = (u + 0x7fffu + ((u >> 16) & 1u)) >> 16;
  return (unsigned short)u;
}
static __device__ __forceinline__ float bf2f(unsigned short s) {
  unsigned u = ((unsigned)s) << 16;
  return __builtin_bit_cast(float, u);
}

// chunked XCD swizzle (bijective: all our grids are multiples of 8)
static __device__ __forceinline__ int xcd_work(int bid, int nwg) {
  int cpx = nwg >> 3;
  return (bid & 7) * cpx + (bid >> 3);
}

// ---------------- fused prep: all converts in ONE kernel ----------------
__global__ __launch_bounds__(256) void prep(const float* __restrict__ x,
                                            const float* __restrict__ wqkv,
                                            const float* __restrict__ wo,
                                            unsigned short* __restrict__ xb,
                                            unsigned short* __restrict__ xT,
                                            unsigned short* __restrict__ wqt,
                                            unsigned short* __restrict__ wk,
                                            unsigned short* __restrict__ wv,
                                            unsigned short* __restrict__ wob) {
  __shared__ unsigned short lds[64][72];
  const int t = threadIdx.x;
  const int bid = blockIdx.x;

  if (bid < 2048) {
    // ---- cvt_x: x[8192][1024] -> xb + xT ----
    const int r0 = (bid & 127) * 64, c0 = (bid >> 7) * 64;
#pragma unroll
    for (int pass = 0; pass < 4; ++pass) {
      int r = pass * 16 + (t >> 4);
      int c = (t & 15) * 4;
      float4 v = *(const float4*)(x + (size_t)(r0 + r) * 1024 + c0 + c);
      u16x4 o = { f2bf(v.x), f2bf(v.y), f2bf(v.z), f2bf(v.w) };
      *(u16x4*)(xb + (size_t)(r0 + r) * 1024 + c0 + c) = o;
#pragma unroll
      for (int j = 0; j < 4; ++j) {
        int C = c + j;
        lds[C][r ^ ((C & 7) << 3)] = o[j];
      }
    }
    __syncthreads();
#pragma unroll
    for (int pass = 0; pass < 2; ++pass) {
      int rr = pass * 32 + (t >> 3);
      int cc = (t & 7) * 8;
      u16x8 v = *(const u16x8*)&lds[rr][cc ^ ((rr & 7) << 3)];
      *(u16x8*)(xT + (size_t)(c0 + rr) * 8192 + r0 + cc) = v;
    }
  } else if (bid < 5120) {
    // ---- cvt_w: row gathers ----
    int row = bid - 2048;            // 0..3071
    const float* src;
    unsigned short* dst;
    if (row < 1024) {
      int h = row >> 6, k = row & 63;
      src = wqkv + (size_t)(h * 192 + 64 + k) * 1024;
      dst = wk + (size_t)row * 1024;
    } else if (row < 2048) {
      int local = row - 1024;
      int h = local >> 6, k = local & 63;
      src = wqkv + (size_t)(h * 192 + 128 + k) * 1024;
      dst = wv + (size_t)local * 1024;
    } else {
      int local = row - 2048;
      src = wo + (size_t)local * 1024;
      dst = wob + (size_t)local * 1024;
    }
    float4 v = *(const float4*)(src + t * 4);
    u16x4 o = { f2bf(v.x), f2bf(v.y), f2bf(v.z), f2bf(v.w) };
    *(u16x4*)(dst + t * 4) = o;
  } else {
    // ---- wqt transpose: wqt[e][h*64+k] = bf16(wqkv[h*192+k][e]) ----
    int tid = bid - 5120;            // 0..255
    const int r0 = (tid & 15) * 64, c0 = (tid >> 4) * 64;
#pragma unroll
    for (int pass = 0; pass < 4; ++pass) {
      int r = pass * 16 + (t >> 4);
      int c = (t & 15) * 4;
      int gr = r0 + r;
      int srcRow = (gr >> 6) * 192 + (gr & 63);
      float4 v = *(const float4*)(wqkv + (size_t)srcRow * 1024 + c0 + c);
      lds[c + 0][r] = f2bf(v.x);
      lds[c + 1][r] = f2bf(v.y);
      lds[c + 2][r] = f2bf(v.z);
      lds[c + 3][r] = f2bf(v.w);
    }
    __syncthreads();
#pragma unroll
    for (int pass = 0; pass < 2; ++pass) {
      int rr = pass * 32 + (t >> 3);
      int cc = (t & 7) * 8;
      *(u16x8*)(wqt + (size_t)(c0 + rr) * 1024 + r0 + cc) = *(const u16x8*)&lds[rr][cc];
    }
  }
}

// ---------------- bt GEMM: 8 waves, double-buffered prefetch, XOR-swizzled LDS ----------------
// LDS[row][slot] = global[row][slot ^ ((row>>1)&3)] (16B slots); read applies same XOR.
template<bool F32OUT>
__global__ __launch_bounds__(512) void gemm_bt(const unsigned short* __restrict__ A, int lda,
                                               long aB, long aP,
                                               const unsigned short* __restrict__ Bm, int ldb,
                                               long bB, long bP,
                                               void* __restrict__ Cv, int ldc,
                                               long cB, long cP,
                                               int K, int psplit, int nx, int ny) {
  __shared__ __align__(16) unsigned short Ash[2][128 * 32];
  __shared__ __align__(16) unsigned short Bsh[2][128 * 32];
  const int work = xcd_work(blockIdx.x, gridDim.x);
  const int xt = work % nx;
  const int yt = (work / nx) % ny;
  const int z  = work / (nx * ny);
  const int bb = z / psplit, pp = z % psplit;
  A  += (size_t)bb * aB + (size_t)pp * aP;
  Bm += (size_t)bb * bB + (size_t)pp * bP;
  const int t = threadIdx.x;
  const int w = t >> 6, l = t & 63;
  const int lr = l & 15, lk = l >> 4;
  const int m0 = yt * 128, n0 = xt * 128;
  const int wr = (w >> 2) * 64, wc = (w & 3) * 32;
  // staging: thread t -> row t>>2, slot t&3; source col pre-swizzled
  const int srow = t >> 2;
  const int skc = ((t & 3) ^ ((srow >> 1) & 3)) << 3;
  const size_t aOff = (size_t)(m0 + srow) * lda + skc;
  const size_t bOff = (size_t)(n0 + srow) * ldb + skc;
  // fragment read swizzle: logical slot lk at row (..+lr) -> slot lk ^ ((lr>>1)&3)
  const int fxor = ((lk ^ ((lr >> 1) & 3)) << 3);
  f32x4 acc[4][2] = {};

  // prologue: stage tile 0 into buf 0
  __builtin_amdgcn_global_load_lds((glb_void*)(A + aOff), (lds_void*)(Ash[0] + w * 512), 16, 0, 0);
  __builtin_amdgcn_global_load_lds((glb_void*)(Bm + bOff), (lds_void*)(Bsh[0] + w * 512), 16, 0, 0);
  __syncthreads();

  int cur = 0;
  for (int k0 = 0; k0 < K; k0 += 32, cur ^= 1) {
    if (k0 + 32 < K) {   // prefetch next tile into buf^1 (overlaps with MFMA below)
      __builtin_amdgcn_global_load_lds((glb_void*)(A + aOff + k0 + 32),
                                       (lds_void*)(Ash[cur ^ 1] + w * 512), 16, 0, 0);
      __builtin_amdgcn_global_load_lds((glb_void*)(Bm + bOff + k0 + 32),
                                       (lds_void*)(Bsh[cur ^ 1] + w * 512), 16, 0, 0);
    }
    bf16x8 af[4], bfv[2];
#pragma unroll
    for (int mi = 0; mi < 4; ++mi)
      af[mi] = *(const bf16x8*)(Ash[cur] + (wr + mi * 16 + lr) * 32 + fxor);
#pragma unroll
    for (int ni = 0; ni < 2; ++ni)
      bfv[ni] = *(const bf16x8*)(Bsh[cur] + (wc + ni * 16 + lr) * 32 + fxor);
#pragma unroll
    for (int mi = 0; mi < 4; ++mi)
#pragma unroll
      for (int ni = 0; ni < 2; ++ni)
        acc[mi][ni] = __builtin_amdgcn_mfma_f32_16x16x32_bf16(af[mi], bfv[ni], acc[mi][ni], 0, 0, 0);
    __syncthreads();   // drains prefetch (vmcnt0) + guards buf reuse
  }

#pragma unroll
  for (int mi = 0; mi < 4; ++mi)
#pragma unroll
    for (int ni = 0; ni < 2; ++ni)
#pragma unroll
      for (int r = 0; r < 4; ++r) {
        const size_t row = (size_t)(m0 + wr + mi * 16 + lk * 4 + r);
        const size_t col = (size_t)(n0 + wc + ni * 16 + lr);
        if constexpr (F32OUT)
          ((float*)Cv)[(size_t)bb * cB + (size_t)pp * cP + row * ldc + col] = acc[mi][ni][r];
        else
          ((unsigned short*)Cv)[(size_t)bb * cB + (size_t)pp * cP + row * ldc + col] = f2bf(acc[mi][ni][r]);
      }
}

// ---------------- triangular Gram GEMM: same dbuf+swizzle engine, K=512 ----------------
__global__ __launch_bounds__(512) void gemm_tri(const unsigned short* __restrict__ xT,
                                                unsigned short* __restrict__ Gp) {
  __shared__ __align__(16) unsigned short Ash[2][128 * 32];
  __shared__ __align__(16) unsigned short Bsh[2][128 * 32];
  const int work = xcd_work(blockIdx.x, gridDim.x);
  int ti = work % 36;
  const int z = work / 36;
  int mt = 0, accum = 0;
  while (accum + mt + 1 <= ti) { accum += mt + 1; ++mt; }
  int nt = ti - accum;
  const int b = z >> 2, p = z & 3;
  const unsigned short* base = xT + (size_t)b * 2048 + (size_t)p * 512;

  const int t = threadIdx.x;
  const int w = t >> 6, l = t & 63;
  const int lr = l & 15, lk = l >> 4;
  const int m0 = mt * 128, n0 = nt * 128;
  const int wr = (w >> 2) * 64, wc = (w & 3) * 32;
  const int srow = t >> 2;
  const int skc = ((t & 3) ^ ((srow >> 1) & 3)) << 3;
  const size_t aOff = (size_t)(m0 + srow) * 8192 + skc;
  const size_t bOff = (size_t)(n0 + srow) * 8192 + skc;
  const int fxor = ((lk ^ ((lr >> 1) & 3)) << 3);
  f32x4 acc[4][2] = {};

  __builtin_amdgcn_global_load_lds((glb_void*)(base + aOff), (lds_void*)(Ash[0] + w * 512), 16, 0, 0);
  __builtin_amdgcn_global_load_lds((glb_void*)(base + bOff), (lds_void*)(Bsh[0] + w * 512), 16, 0, 0);
  __syncthreads();

  int cur = 0;
  for (int k0 = 0; k0 < 512; k0 += 32, cur ^= 1) {
    if (k0 + 32 < 512) {
      __builtin_amdgcn_global_load_lds((glb_void*)(base + aOff + k0 + 32),
                                       (lds_void*)(Ash[cur ^ 1] + w * 512), 16, 0, 0);
      __builtin_amdgcn_global_load_lds((glb_void*)(base + bOff + k0 + 32),
                                       (lds_void*)(Bsh[cur ^ 1] + w * 512), 16, 0, 0);
    }
    bf16x8 af[4], bfv[2];
#pragma unroll
    for (int mi = 0; mi < 4; ++mi)
      af[mi] = *(const bf16x8*)(Ash[cur] + (wr + mi * 16 + lr) * 32 + fxor);
#pragma unroll
    for (int ni = 0; ni < 2; ++ni)
      bfv[ni] = *(const bf16x8*)(Bsh[cur] + (wc + ni * 16 + lr) * 32 + fxor);
#pragma unroll
    for (int mi = 0; mi < 4; ++mi)
#pragma unroll
      for (int ni = 0; ni < 2; ++ni)
        acc[mi][ni] = __builtin_amdgcn_mfma_f32_16x16x32_bf16(af[mi], bfv[ni], acc[mi][ni], 0, 0, 0);
    __syncthreads();
  }

  unsigned short* out = Gp + (size_t)z * 1048576;
#pragma unroll
  for (int mi = 0; mi < 4; ++mi)
#pragma unroll
    for (int ni = 0; ni < 2; ++ni)
#pragma unroll
      for (int r = 0; r < 4; ++r)
        out[(size_t)(m0 + wr + mi * 16 + lk * 4 + r) * 1024 + n0 + wc + ni * 16 + lr]
            = f2bf(acc[mi][ni][r]);
}

// ---------------- mirror+reduce via LDS transpose ----------------
__global__ __launch_bounds__(256) void mirror_reduce(const unsigned short* __restrict__ Gp,
                                                     unsigned short* __restrict__ G) {
  __shared__ unsigned short ldsT[128][128];
  int ti = blockIdx.x;
  int mt = 0, accum = 0;
  while (accum + mt + 1 <= ti) { accum += mt + 1; ++mt; }
  int nt = ti - accum;
  const int b = blockIdx.y;
  const int m0 = mt * 128, n0 = nt * 128;
  const unsigned short* base = Gp + (size_t)b * 4 * 1048576;
  unsigned short* Gb = G + (size_t)b * 1048576;
  const int t = threadIdx.x;

#pragma unroll
  for (int pass = 0; pass < 8; ++pass) {
    int idx = pass * 2048 + t * 8;
    int r = idx >> 7, c = idx & 127;
    float s[8] = {};
#pragma unroll
    for (int p = 0; p < 4; ++p) {
      u16x8 v = *(const u16x8*)(base + (size_t)p * 1048576 + (size_t)(m0 + r) * 1024 + n0 + c);
#pragma unroll
      for (int j = 0; j < 8; ++j) s[j] += bf2f(v[j]);
    }
    u16x8 o;
#pragma unroll
    for (int j = 0; j < 8; ++j) o[j] = f2bf(s[j]);
    *(u16x8*)(Gb + (size_t)(m0 + r) * 1024 + n0 + c) = o;
#pragma unroll
    for (int j = 0; j < 8; ++j) {
      int col = c + j;
      ldsT[col][r ^ (((col >> 3) & 7) << 3)] = o[j];
    }
  }

  if (mt != nt) {
    __syncthreads();
#pragma unroll
    for (int pass = 0; pass < 8; ++pass) {
      int idx = pass * 2048 + t * 8;
      int rr = idx >> 7, cc = idx & 127;
      u16x8 v = *(const u16x8*)&ldsT[rr][cc ^ (((rr >> 3) & 7) << 3)];
      *(u16x8*)(Gb + (size_t)(n0 + rr) * 1024 + m0 + cc) = v;
    }
  }
}

// ---------------- Mp[bh][ep][k][d'] partials ----------------
__global__ __launch_bounds__(256) void mt_partial(const unsigned short* __restrict__ T1p,
                                                  const unsigned short* __restrict__ wv,
                                                  float* __restrict__ Mp) {
  __shared__ float Msh[4096];   // [k][d'] linear
  const int t = threadIdx.x;
  const int w = t >> 6, l = t & 63;
  const int lr = l & 15, lk = l >> 4;
  const int bh = blockIdx.x, ep = blockIdx.y;
  const int b = bh >> 4, h = bh & 15;
  const int p = w >> 1, half = w & 1;

  for (int i = t; i < 4096; i += 256) Msh[i] = 0.f;
  __syncthreads();

  const unsigned short* Ab = T1p + (size_t)(b * 2 + p) * 1048576 + (size_t)(h * 64) * 1024;
  const unsigned short* Bb = wv + (size_t)(h * 64) * 1024;
  f32x4 acc[4][4] = {};
  const int ebeg = ep * 256 + half * 128;
#pragma unroll
  for (int e0 = ebeg; e0 < ebeg + 128; e0 += 32) {
    bf16x8 af[4], bfv[4];
#pragma unroll
    for (int mi = 0; mi < 4; ++mi)
      af[mi] = *(const bf16x8*)(Ab + (size_t)(mi * 16 + lr) * 1024 + e0 + lk * 8);
#pragma unroll
    for (int ni = 0; ni < 4; ++ni)
      bfv[ni] = *(const bf16x8*)(Bb + (size_t)(ni * 16 + lr) * 1024 + e0 + lk * 8);
#pragma unroll
    for (int mi = 0; mi < 4; ++mi)
#pragma unroll
      for (int ni = 0; ni < 4; ++ni)
        acc[mi][ni] = __builtin_amdgcn_mfma_f32_16x16x32_bf16(af[mi], bfv[ni], acc[mi][ni], 0, 0, 0);
  }
#pragma unroll
  for (int mi = 0; mi < 4; ++mi)
#pragma unroll
    for (int ni = 0; ni < 4; ++ni)
#pragma unroll
      for (int r = 0; r < 4; ++r)
        atomicAdd(&Msh[(mi * 16 + lk * 4 + r) * 64 + ni * 16 + lr], acc[mi][ni][r]);
  __syncthreads();

  float* out = Mp + ((size_t)bh * 4 + ep) * 4096;
  for (int i = t * 4; i < 4096; i += 1024)
    *(float4*)(out + i) = *(const float4*)&Msh[i];
}

// ---------------- fused: reduce Mp -> Mt (LDS) -> Amat slice ----------------
__global__ __launch_bounds__(256) void amat_fused(const float* __restrict__ Mp,
                                                  const unsigned short* __restrict__ wqt,
                                                  unsigned short* __restrict__ Amat) {
  __shared__ float Msh[64 * 68];            // [k][dp], padded row 68
  __shared__ unsigned short MtSh[64][80];   // [dp][k], padded row 80
  const int t = threadIdx.x;
  const int et = blockIdx.x, bh = blockIdx.y;
  const int b = bh >> 4, h = bh & 15;

  const float* base = Mp + (size_t)bh * 16384;
  for (int i = t * 4; i < 4096; i += 1024) {
    float4 s = *(const float4*)(base + i);
#pragma unroll
    for (int p = 1; p < 4; ++p) {
      float4 v = *(const float4*)(base + p * 4096 + i);
      s.x += v.x; s.y += v.y; s.z += v.z; s.w += v.w;
    }
    int k = i >> 6, dp = i & 63;
    *(float4*)&Msh[k * 68 + dp] = s;
  }
  __syncthreads();

  for (int i = t; i < 4096; i += 256) {
    int dp = i >> 6, k = i & 63;
    MtSh[dp][k] = f2bf(Msh[k * 68 + dp] * SCALE_F);
  }
  __syncthreads();

  const int w = t >> 6, l = t & 63;
  const int lr = l & 15, lk = l >> 4;
  const int e0 = et * 128 + w * 32;

  f32x4 acc[2][4] = {};
#pragma unroll
  for (int ks = 0; ks < 2; ++ks) {
    bf16x8 af[2], bfv[4];
#pragma unroll
    for (int mi = 0; mi < 2; ++mi)
      af[mi] = *(const bf16x8*)(wqt + (size_t)(e0 + mi * 16 + lr) * 1024 + h * 64 + ks * 32 + lk * 8);
#pragma unroll
    for (int ni = 0; ni < 4; ++ni)
      bfv[ni] = *(const bf16x8*)(&MtSh[ni * 16 + lr][ks * 32 + lk * 8]);
#pragma unroll
    for (int mi = 0; mi < 2; ++mi)
#pragma unroll
      for (int ni = 0; ni < 4; ++ni)
        acc[mi][ni] = __builtin_amdgcn_mfma_f32_16x16x32_bf16(af[mi], bfv[ni], acc[mi][ni], 0, 0, 0);
  }
#pragma unroll
  for (int mi = 0; mi < 2; ++mi)
#pragma unroll
    for (int ni = 0; ni < 4; ++ni)
#pragma unroll
      for (int r = 0; r < 4; ++r)
        Amat[(size_t)b * 1048576 + (size_t)(e0 + mi * 16 + lk * 4 + r) * 1024 + h * 64 + ni * 16 + lr]
            = f2bf(acc[mi][ni][r]);
}

// ---------------- launch ----------------
extern "C" void kernel_launch(void* const* d_in, const int* in_sizes, int n_in,
                              void* d_out, int out_size, void* d_ws, size_t ws_size,
                              hipStream_t stream) {
  const float* x    = (const float*)d_in[0];   // [4,2048,1024]
  const float* wqkv = (const float*)d_in[1];   // [3072,1024]
  const float* wo   = (const float*)d_in[2];   // [1024,1024]
  float* out = (float*)d_out;                  // [4,2048,1024] fp32

  char* ws = (char*)d_ws;
  const size_t MB = 1048576;
  unsigned short* xb   = (unsigned short*)(ws + 0);        // 16MB [8192][1024]
  unsigned short* xT   = (unsigned short*)(ws + 16 * MB);  // 16MB [1024][8192]
  unsigned short* wqt  = (unsigned short*)(ws + 32 * MB);  // 2MB
  unsigned short* wk   = (unsigned short*)(ws + 34 * MB);  // 2MB
  unsigned short* wv   = (unsigned short*)(ws + 36 * MB);  // 2MB
  unsigned short* wob  = (unsigned short*)(ws + 38 * MB);  // 2MB
  unsigned short* Gp   = (unsigned short*)(ws + 40 * MB);  // 32MB [4b][4p][1024][1024] (lower tiles)
  unsigned short* G    = (unsigned short*)(ws + 72 * MB);  // 8MB  [4b][1024][1024]  -> peak 80MB
  // reuse dead regions:
  unsigned short* T1p  = (unsigned short*)(ws + 40 * MB);  // 16MB [4b][2p][1024][1024] (over dead Gp)
  float*          Mp   = (float*)        (ws + 56 * MB);   // 4MB  [64 bh][4 ep][64][64] f32
  unsigned short* Amat = (unsigned short*)(ws + 61 * MB);  // 8MB  [4b][1024 e][1024 i]
  unsigned short* Weff = (unsigned short*)(ws + 40 * MB);  // 8MB  (over dead T1p)

  const long M1 = 1048576;

  // all converts in one launch
  prep<<<5376, 256, 0, stream>>>(x, wqkv, wo, xb, xT, wqt, wk, wv, wob);

  // G_b = x_b^T x_b : lower triangle, split-K x4 (576 blocks, swizzled, 8 waves, dbuf)
  gemm_tri<<<576, 512, 0, stream>>>(xT, Gp);
  mirror_reduce<<<dim3(36, 4), 256, 0, stream>>>(Gp, G);

  // T1_b = wk @ G_b (G symmetric), split-K x2 (512 blocks, swizzled, 8 waves, dbuf)
  gemm_bt<false><<<512, 512, 0, stream>>>(wk, 1024, 0, 512,
                                          G, 1024, M1, 512,
                                          (void*)T1p, 1024, 2 * M1, M1, 512, 2, 8, 8);

  // M partials: 256 blocks, f32 out
  mt_partial<<<dim3(64, 4), 256, 0, stream>>>(T1p, wv, Mp);

  // fused: reduce Mp -> Mt -> Amat_b = Wq^T * blockdiag(SCALE*M_b)   (512 blocks)
  amat_fused<<<dim3(8, 64), 256, 0, stream>>>(Mp, wqt, Amat);

  // Weff_b[j][e] = sum_i wo[j][i] * Amat_b[e][i]   (256 blocks, dbuf)
  gemm_bt<false><<<256, 512, 0, stream>>>(wob, 1024, 0, 0,
                                          Amat, 1024, M1, 0,
                                          (void*)Weff, 1024, M1, 0, 1024, 1, 8, 8);

  // out_b = x_b @ Weff_b^T  (fp32 out; 512 blocks, dbuf)
  gemm_bt<true><<<512, 512, 0, stream>>>(xb, 1024, 2048 * 1024L, 0,
                                         Weff, 1024, M1, 0,
                                         (void*)out, 1024, 2048 * 1024L, 0, 1024, 1, 8, 16);
}

// Round 9
// 122.580 us; speedup vs baseline: 1.8433x; 1.1837x over previous
//
#include <hip/hip_runtime.h>
#include <hip/hip_bf16.h>
#include <cstdint>

// B=4, S=2048, E=1024, H=16, D=64, SCALE = 1/8
#define SCALE_F 0.125f

typedef __attribute__((ext_vector_type(8))) short bf16x8;
typedef __attribute__((ext_vector_type(4))) float f32x4;
typedef __attribute__((ext_vector_type(4))) unsigned short u16x4;
typedef __attribute__((ext_vector_type(8))) unsigned short u16x8;

typedef const __attribute__((address_space(1))) void glb_void;
typedef __attribute__((address_space(3))) void lds_void;

static __device__ __forceinline__ unsigned short f2bf(float f) {
  unsigned u = __builtin_bit_cast(unsigned, f);
  u = (u + 0x7fffu + ((u >> 16) & 1u)) >> 16;
  return (unsigned short)u;
}
static __device__ __forceinline__ float bf2f(unsigned short s) {
  unsigned u = ((unsigned)s) << 16;
  return __builtin_bit_cast(float, u);
}

// chunked XCD swizzle (bijective: all our grids are multiples of 8)
static __device__ __forceinline__ int xcd_work(int bid, int nwg) {
  int cpx = nwg >> 3;
  return (bid & 7) * cpx + (bid >> 3);
}

// ---------------- fused prep: all converts in ONE kernel ----------------
__global__ __launch_bounds__(256) void prep(const float* __restrict__ x,
                                            const float* __restrict__ wqkv,
                                            const float* __restrict__ wo,
                                            unsigned short* __restrict__ xb,
                                            unsigned short* __restrict__ xT,
                                            unsigned short* __restrict__ wqt,
                                            unsigned short* __restrict__ wk,
                                            unsigned short* __restrict__ wv,
                                            unsigned short* __restrict__ wob) {
  __shared__ unsigned short lds[64][72];
  const int t = threadIdx.x;
  const int bid = blockIdx.x;

  if (bid < 2048) {
    // ---- cvt_x: x[8192][1024] -> xb + xT ----
    const int r0 = (bid & 127) * 64, c0 = (bid >> 7) * 64;
#pragma unroll
    for (int pass = 0; pass < 4; ++pass) {
      int r = pass * 16 + (t >> 4);
      int c = (t & 15) * 4;
      float4 v = *(const float4*)(x + (size_t)(r0 + r) * 1024 + c0 + c);
      u16x4 o = { f2bf(v.x), f2bf(v.y), f2bf(v.z), f2bf(v.w) };
      *(u16x4*)(xb + (size_t)(r0 + r) * 1024 + c0 + c) = o;
#pragma unroll
      for (int j = 0; j < 4; ++j) {
        int C = c + j;
        lds[C][r ^ ((C & 7) << 3)] = o[j];
      }
    }
    __syncthreads();
#pragma unroll
    for (int pass = 0; pass < 2; ++pass) {
      int rr = pass * 32 + (t >> 3);
      int cc = (t & 7) * 8;
      u16x8 v = *(const u16x8*)&lds[rr][cc ^ ((rr & 7) << 3)];
      *(u16x8*)(xT + (size_t)(c0 + rr) * 8192 + r0 + cc) = v;
    }
  } else if (bid < 5120) {
    // ---- cvt_w: row gathers ----
    int row = bid - 2048;            // 0..3071
    const float* src;
    unsigned short* dst;
    if (row < 1024) {
      int h = row >> 6, k = row & 63;
      src = wqkv + (size_t)(h * 192 + 64 + k) * 1024;
      dst = wk + (size_t)row * 1024;
    } else if (row < 2048) {
      int local = row - 1024;
      int h = local >> 6, k = local & 63;
      src = wqkv + (size_t)(h * 192 + 128 + k) * 1024;
      dst = wv + (size_t)local * 1024;
    } else {
      int local = row - 2048;
      src = wo + (size_t)local * 1024;
      dst = wob + (size_t)local * 1024;
    }
    float4 v = *(const float4*)(src + t * 4);
    u16x4 o = { f2bf(v.x), f2bf(v.y), f2bf(v.z), f2bf(v.w) };
    *(u16x4*)(dst + t * 4) = o;
  } else {
    // ---- wqt transpose: wqt[e][h*64+k] = bf16(wqkv[h*192+k][e]) ----
    int tid = bid - 5120;            // 0..255
    const int r0 = (tid & 15) * 64, c0 = (tid >> 4) * 64;
#pragma unroll
    for (int pass = 0; pass < 4; ++pass) {
      int r = pass * 16 + (t >> 4);
      int c = (t & 15) * 4;
      int gr = r0 + r;
      int srcRow = (gr >> 6) * 192 + (gr & 63);
      float4 v = *(const float4*)(wqkv + (size_t)srcRow * 1024 + c0 + c);
      lds[c + 0][r] = f2bf(v.x);
      lds[c + 1][r] = f2bf(v.y);
      lds[c + 2][r] = f2bf(v.z);
      lds[c + 3][r] = f2bf(v.w);
    }
    __syncthreads();
#pragma unroll
    for (int pass = 0; pass < 2; ++pass) {
      int rr = pass * 32 + (t >> 3);
      int cc = (t & 7) * 8;
      *(u16x8*)(wqt + (size_t)(c0 + rr) * 1024 + r0 + cc) = *(const u16x8*)&lds[rr][cc];
    }
  }
}

// ---------------- bt GEMM: 8 waves, double-buffered prefetch, XOR-swizzled LDS ----------------
template<bool F32OUT>
__global__ __launch_bounds__(512) void gemm_bt(const unsigned short* __restrict__ A, int lda,
                                               long aB, long aP,
                                               const unsigned short* __restrict__ Bm, int ldb,
                                               long bB, long bP,
                                               void* __restrict__ Cv, int ldc,
                                               long cB, long cP,
                                               int K, int psplit, int nx, int ny) {
  __shared__ __align__(16) unsigned short Ash[2][128 * 32];
  __shared__ __align__(16) unsigned short Bsh[2][128 * 32];
  const int work = xcd_work(blockIdx.x, gridDim.x);
  const int xt = work % nx;
  const int yt = (work / nx) % ny;
  const int z  = work / (nx * ny);
  const int bb = z / psplit, pp = z % psplit;
  A  += (size_t)bb * aB + (size_t)pp * aP;
  Bm += (size_t)bb * bB + (size_t)pp * bP;
  const int t = threadIdx.x;
  const int w = t >> 6, l = t & 63;
  const int lr = l & 15, lk = l >> 4;
  const int m0 = yt * 128, n0 = xt * 128;
  const int wr = (w >> 2) * 64, wc = (w & 3) * 32;
  const int srow = t >> 2;
  const int skc = ((t & 3) ^ ((srow >> 1) & 3)) << 3;
  const size_t aOff = (size_t)(m0 + srow) * lda + skc;
  const size_t bOff = (size_t)(n0 + srow) * ldb + skc;
  const int fxor = ((lk ^ ((lr >> 1) & 3)) << 3);
  f32x4 acc[4][2] = {};

  __builtin_amdgcn_global_load_lds((glb_void*)(A + aOff), (lds_void*)(Ash[0] + w * 512), 16, 0, 0);
  __builtin_amdgcn_global_load_lds((glb_void*)(Bm + bOff), (lds_void*)(Bsh[0] + w * 512), 16, 0, 0);
  __syncthreads();

  int cur = 0;
  for (int k0 = 0; k0 < K; k0 += 32, cur ^= 1) {
    if (k0 + 32 < K) {
      __builtin_amdgcn_global_load_lds((glb_void*)(A + aOff + k0 + 32),
                                       (lds_void*)(Ash[cur ^ 1] + w * 512), 16, 0, 0);
      __builtin_amdgcn_global_load_lds((glb_void*)(Bm + bOff + k0 + 32),
                                       (lds_void*)(Bsh[cur ^ 1] + w * 512), 16, 0, 0);
    }
    bf16x8 af[4], bfv[2];
#pragma unroll
    for (int mi = 0; mi < 4; ++mi)
      af[mi] = *(const bf16x8*)(Ash[cur] + (wr + mi * 16 + lr) * 32 + fxor);
#pragma unroll
    for (int ni = 0; ni < 2; ++ni)
      bfv[ni] = *(const bf16x8*)(Bsh[cur] + (wc + ni * 16 + lr) * 32 + fxor);
#pragma unroll
    for (int mi = 0; mi < 4; ++mi)
#pragma unroll
      for (int ni = 0; ni < 2; ++ni)
        acc[mi][ni] = __builtin_amdgcn_mfma_f32_16x16x32_bf16(af[mi], bfv[ni], acc[mi][ni], 0, 0, 0);
    __syncthreads();
  }

#pragma unroll
  for (int mi = 0; mi < 4; ++mi)
#pragma unroll
    for (int ni = 0; ni < 2; ++ni)
#pragma unroll
      for (int r = 0; r < 4; ++r) {
        const size_t row = (size_t)(m0 + wr + mi * 16 + lk * 4 + r);
        const size_t col = (size_t)(n0 + wc + ni * 16 + lr);
        if constexpr (F32OUT)
          ((float*)Cv)[(size_t)bb * cB + (size_t)pp * cP + row * ldc + col] = acc[mi][ni][r];
        else
          ((unsigned short*)Cv)[(size_t)bb * cB + (size_t)pp * cP + row * ldc + col] = f2bf(acc[mi][ni][r]);
      }
}

// ---------------- triangular Gram GEMM: dbuf+swizzle engine, K=512 ----------------
__global__ __launch_bounds__(512) void gemm_tri(const unsigned short* __restrict__ xT,
                                                unsigned short* __restrict__ Gp) {
  __shared__ __align__(16) unsigned short Ash[2][128 * 32];
  __shared__ __align__(16) unsigned short Bsh[2][128 * 32];
  const int work = xcd_work(blockIdx.x, gridDim.x);
  int ti = work % 36;
  const int z = work / 36;
  int mt = 0, accum = 0;
  while (accum + mt + 1 <= ti) { accum += mt + 1; ++mt; }
  int nt = ti - accum;
  const int b = z >> 2, p = z & 3;
  const unsigned short* base = xT + (size_t)b * 2048 + (size_t)p * 512;

  const int t = threadIdx.x;
  const int w = t >> 6, l = t & 63;
  const int lr = l & 15, lk = l >> 4;
  const int m0 = mt * 128, n0 = nt * 128;
  const int wr = (w >> 2) * 64, wc = (w & 3) * 32;
  const int srow = t >> 2;
  const int skc = ((t & 3) ^ ((srow >> 1) & 3)) << 3;
  const size_t aOff = (size_t)(m0 + srow) * 8192 + skc;
  const size_t bOff = (size_t)(n0 + srow) * 8192 + skc;
  const int fxor = ((lk ^ ((lr >> 1) & 3)) << 3);
  f32x4 acc[4][2] = {};

  __builtin_amdgcn_global_load_lds((glb_void*)(base + aOff), (lds_void*)(Ash[0] + w * 512), 16, 0, 0);
  __builtin_amdgcn_global_load_lds((glb_void*)(base + bOff), (lds_void*)(Bsh[0] + w * 512), 16, 0, 0);
  __syncthreads();

  int cur = 0;
  for (int k0 = 0; k0 < 512; k0 += 32, cur ^= 1) {
    if (k0 + 32 < 512) {
      __builtin_amdgcn_global_load_lds((glb_void*)(base + aOff + k0 + 32),
                                       (lds_void*)(Ash[cur ^ 1] + w * 512), 16, 0, 0);
      __builtin_amdgcn_global_load_lds((glb_void*)(base + bOff + k0 + 32),
                                       (lds_void*)(Bsh[cur ^ 1] + w * 512), 16, 0, 0);
    }
    bf16x8 af[4], bfv[2];
#pragma unroll
    for (int mi = 0; mi < 4; ++mi)
      af[mi] = *(const bf16x8*)(Ash[cur] + (wr + mi * 16 + lr) * 32 + fxor);
#pragma unroll
    for (int ni = 0; ni < 2; ++ni)
      bfv[ni] = *(const bf16x8*)(Bsh[cur] + (wc + ni * 16 + lr) * 32 + fxor);
#pragma unroll
    for (int mi = 0; mi < 4; ++mi)
#pragma unroll
      for (int ni = 0; ni < 2; ++ni)
        acc[mi][ni] = __builtin_amdgcn_mfma_f32_16x16x32_bf16(af[mi], bfv[ni], acc[mi][ni], 0, 0, 0);
    __syncthreads();
  }

  unsigned short* out = Gp + (size_t)z * 1048576;
#pragma unroll
  for (int mi = 0; mi < 4; ++mi)
#pragma unroll
    for (int ni = 0; ni < 2; ++ni)
#pragma unroll
      for (int r = 0; r < 4; ++r)
        out[(size_t)(m0 + wr + mi * 16 + lk * 4 + r) * 1024 + n0 + wc + ni * 16 + lr]
            = f2bf(acc[mi][ni][r]);
}

// ---------------- mirror+reduce via LDS transpose ----------------
__global__ __launch_bounds__(256) void mirror_reduce(const unsigned short* __restrict__ Gp,
                                                     unsigned short* __restrict__ G) {
  __shared__ unsigned short ldsT[128][128];
  int ti = blockIdx.x;
  int mt = 0, accum = 0;
  while (accum + mt + 1 <= ti) { accum += mt + 1; ++mt; }
  int nt = ti - accum;
  const int b = blockIdx.y;
  const int m0 = mt * 128, n0 = nt * 128;
  const unsigned short* base = Gp + (size_t)b * 4 * 1048576;
  unsigned short* Gb = G + (size_t)b * 1048576;
  const int t = threadIdx.x;

#pragma unroll
  for (int pass = 0; pass < 8; ++pass) {
    int idx = pass * 2048 + t * 8;
    int r = idx >> 7, c = idx & 127;
    float s[8] = {};
#pragma unroll
    for (int p = 0; p < 4; ++p) {
      u16x8 v = *(const u16x8*)(base + (size_t)p * 1048576 + (size_t)(m0 + r) * 1024 + n0 + c);
#pragma unroll
      for (int j = 0; j < 8; ++j) s[j] += bf2f(v[j]);
    }
    u16x8 o;
#pragma unroll
    for (int j = 0; j < 8; ++j) o[j] = f2bf(s[j]);
    *(u16x8*)(Gb + (size_t)(m0 + r) * 1024 + n0 + c) = o;
#pragma unroll
    for (int j = 0; j < 8; ++j) {
      int col = c + j;
      ldsT[col][r ^ (((col >> 3) & 7) << 3)] = o[j];
    }
  }

  if (mt != nt) {
    __syncthreads();
#pragma unroll
    for (int pass = 0; pass < 8; ++pass) {
      int idx = pass * 2048 + t * 8;
      int rr = idx >> 7, cc = idx & 127;
      u16x8 v = *(const u16x8*)&ldsT[rr][cc ^ (((rr >> 3) & 7) << 3)];
      *(u16x8*)(Gb + (size_t)(n0 + rr) * 1024 + m0 + cc) = v;
    }
  }
}

// ---------------- mdirect: Mp[bh][es] = wk_h @ G_b[e-slice] then @ wv_h-slice^T ----------------
// grid 512 = (bh 64) x (es 8), 512 threads (8 waves).
// phase 1: U[64 i][128 e] = sum_k wk[h*64+i][k] * G_b[e0+e][k]  (G symmetric -> rows)
// phase 2: Mp[i][j] = sum_e U[i][e] * wv[h*64+j][e0+e]  (f32 partial out)
__global__ __launch_bounds__(512) void mdirect(const unsigned short* __restrict__ wk,
                                               const unsigned short* __restrict__ G,
                                               const unsigned short* __restrict__ wv,
                                               float* __restrict__ Mp) {
  __shared__ __align__(16) unsigned short Awk[2][64 * 32];
  __shared__ __align__(16) unsigned short Bg[2][128 * 32];
  __shared__ __align__(16) unsigned short Ut[64 * 128];
  __shared__ __align__(16) unsigned short WvS[64 * 128];
  const int work = xcd_work(blockIdx.x, gridDim.x);
  const int bh = work >> 3, es = work & 7;
  const int b = bh >> 4, h = bh & 15;
  const int e0 = es * 128;
  const int t = threadIdx.x;
  const int w = t >> 6, l = t & 63;
  const int lr = l & 15, lk = l >> 4;

  const unsigned short* wkB = wk + (size_t)(h * 64) * 1024;
  const unsigned short* Gb  = G + (size_t)b * 1048576 + (size_t)e0 * 1024;
  const unsigned short* wvB = wv + (size_t)(h * 64) * 1024 + e0;

  // staging indices (phase 1): A 64x32 = 256 loads (waves 0-3), B 128x32 = 512 loads
  const int arow = t >> 2, askc = ((t & 3) ^ ((arow >> 1) & 3)) << 3;   // t<256 only
  const int brow = t >> 2, bskc = ((t & 3) ^ ((brow >> 1) & 3)) << 3;
  const size_t aOff = (size_t)arow * 1024 + askc;
  const size_t bOff = (size_t)brow * 1024 + bskc;
  const int fxor = ((lk ^ ((lr >> 1) & 3)) << 3);

  // prologue: stage wv slice (64x128, slot-swizzled src) + tile 0
#pragma unroll
  for (int i = 0; i < 2; ++i) {
    int idx = i * 512 + t;                 // 0..1023
    int row = idx >> 4, slot = idx & 15;
    int sslot = slot ^ (row & 15);
    __builtin_amdgcn_global_load_lds(
        (glb_void*)(wvB + (size_t)row * 1024 + sslot * 8),
        (lds_void*)(WvS + i * 4096 + w * 512), 16, 0, 0);
  }
  if (t < 256)
    __builtin_amdgcn_global_load_lds((glb_void*)(wkB + aOff),
                                     (lds_void*)(Awk[0] + w * 512), 16, 0, 0);
  __builtin_amdgcn_global_load_lds((glb_void*)(Gb + bOff),
                                   (lds_void*)(Bg[0] + w * 512), 16, 0, 0);
  __syncthreads();

  // phase 1: K-loop over k (1024), wave owns 64m x 16n (wc = w*16), acc[4][1]
  const int wc = w * 16;
  f32x4 acc[4] = {};
  int cur = 0;
  for (int k0 = 0; k0 < 1024; k0 += 32, cur ^= 1) {
    if (k0 + 32 < 1024) {
      if (t < 256)
        __builtin_amdgcn_global_load_lds((glb_void*)(wkB + aOff + k0 + 32),
                                         (lds_void*)(Awk[cur ^ 1] + w * 512), 16, 0, 0);
      __builtin_amdgcn_global_load_lds((glb_void*)(Gb + bOff + k0 + 32),
                                       (lds_void*)(Bg[cur ^ 1] + w * 512), 16, 0, 0);
    }
    bf16x8 af[4], bfv;
#pragma unroll
    for (int mi = 0; mi < 4; ++mi)
      af[mi] = *(const bf16x8*)(Awk[cur] + (mi * 16 + lr) * 32 + fxor);
    bfv = *(const bf16x8*)(Bg[cur] + (wc + lr) * 32 + fxor);
#pragma unroll
    for (int mi = 0; mi < 4; ++mi)
      acc[mi] = __builtin_amdgcn_mfma_f32_16x16x32_bf16(af[mi], bfv, acc[mi], 0, 0, 0);
    __syncthreads();
  }

  // write U (bf16) into swizzled LDS: U[row i][col e] at slot (col>>3)^(i&15)
#pragma unroll
  for (int mi = 0; mi < 4; ++mi)
#pragma unroll
    for (int r = 0; r < 4; ++r) {
      int i = mi * 16 + lk * 4 + r;
      int col = wc + lr;
      int addr = i * 128 + ((((col >> 3) ^ (i & 15)) << 3) | (col & 7));
      Ut[addr] = f2bf(acc[mi][r]);
    }
  __syncthreads();

  // phase 2 (waves 0-3): M[16 rows each][64 j], K=128 over e
  if (w < 4) {
    f32x4 acc2[4] = {};
#pragma unroll
    for (int ks = 0; ks < 4; ++ks) {
      int slot = (ks << 2) | lk;
      bf16x8 a2 = *(const bf16x8*)(Ut + (w * 16 + lr) * 128 + ((slot ^ lr) << 3));
      bf16x8 b2[4];
#pragma unroll
      for (int ni = 0; ni < 4; ++ni)
        b2[ni] = *(const bf16x8*)(WvS + (ni * 16 + lr) * 128 + ((slot ^ lr) << 3));
#pragma unroll
      for (int ni = 0; ni < 4; ++ni)
        acc2[ni] = __builtin_amdgcn_mfma_f32_16x16x32_bf16(a2, b2[ni], acc2[ni], 0, 0, 0);
    }
    float* out = Mp + ((size_t)bh * 8 + es) * 4096;
#pragma unroll
    for (int ni = 0; ni < 4; ++ni)
#pragma unroll
      for (int r = 0; r < 4; ++r)
        out[(w * 16 + lk * 4 + r) * 64 + ni * 16 + lr] = acc2[ni][r];
  }
}

// ---------------- fused: reduce Mp (8 partials) -> Mt (LDS) -> Amat slice ----------------
__global__ __launch_bounds__(256) void amat_fused(const float* __restrict__ Mp,
                                                  const unsigned short* __restrict__ wqt,
                                                  unsigned short* __restrict__ Amat) {
  __shared__ float Msh[64 * 68];            // [k][dp], padded row 68
  __shared__ unsigned short MtSh[64][80];   // [dp][k], padded row 80
  const int t = threadIdx.x;
  const int et = blockIdx.x, bh = blockIdx.y;
  const int b = bh >> 4, h = bh & 15;

  const float* base = Mp + (size_t)bh * 32768;
  for (int i = t * 4; i < 4096; i += 1024) {
    float4 s = *(const float4*)(base + i);
#pragma unroll
    for (int p = 1; p < 8; ++p) {
      float4 v = *(const float4*)(base + p * 4096 + i);
      s.x += v.x; s.y += v.y; s.z += v.z; s.w += v.w;
    }
    int k = i >> 6, dp = i & 63;
    *(float4*)&Msh[k * 68 + dp] = s;
  }
  __syncthreads();

  for (int i = t; i < 4096; i += 256) {
    int dp = i >> 6, k = i & 63;
    MtSh[dp][k] = f2bf(Msh[k * 68 + dp] * SCALE_F);
  }
  __syncthreads();

  const int w = t >> 6, l = t & 63;
  const int lr = l & 15, lk = l >> 4;
  const int e0 = et * 128 + w * 32;

  f32x4 acc[2][4] = {};
#pragma unroll
  for (int ks = 0; ks < 2; ++ks) {
    bf16x8 af[2], bfv[4];
#pragma unroll
    for (int mi = 0; mi < 2; ++mi)
      af[mi] = *(const bf16x8*)(wqt + (size_t)(e0 + mi * 16 + lr) * 1024 + h * 64 + ks * 32 + lk * 8);
#pragma unroll
    for (int ni = 0; ni < 4; ++ni)
      bfv[ni] = *(const bf16x8*)(&MtSh[ni * 16 + lr][ks * 32 + lk * 8]);
#pragma unroll
    for (int mi = 0; mi < 2; ++mi)
#pragma unroll
      for (int ni = 0; ni < 4; ++ni)
        acc[mi][ni] = __builtin_amdgcn_mfma_f32_16x16x32_bf16(af[mi], bfv[ni], acc[mi][ni], 0, 0, 0);
  }
#pragma unroll
  for (int mi = 0; mi < 2; ++mi)
#pragma unroll
    for (int ni = 0; ni < 4; ++ni)
#pragma unroll
      for (int r = 0; r < 4; ++r)
        Amat[(size_t)b * 1048576 + (size_t)(e0 + mi * 16 + lk * 4 + r) * 1024 + h * 64 + ni * 16 + lr]
            = f2bf(acc[mi][ni][r]);
}

// ---------------- launch ----------------
extern "C" void kernel_launch(void* const* d_in, const int* in_sizes, int n_in,
                              void* d_out, int out_size, void* d_ws, size_t ws_size,
                              hipStream_t stream) {
  const float* x    = (const float*)d_in[0];   // [4,2048,1024]
  const float* wqkv = (const float*)d_in[1];   // [3072,1024]
  const float* wo   = (const float*)d_in[2];   // [1024,1024]
  float* out = (float*)d_out;                  // [4,2048,1024] fp32

  char* ws = (char*)d_ws;
  const size_t MB = 1048576;
  unsigned short* xb   = (unsigned short*)(ws + 0);        // 16MB [8192][1024]
  unsigned short* xT   = (unsigned short*)(ws + 16 * MB);  // 16MB [1024][8192]
  unsigned short* wqt  = (unsigned short*)(ws + 32 * MB);  // 2MB
  unsigned short* wk   = (unsigned short*)(ws + 34 * MB);  // 2MB
  unsigned short* wv   = (unsigned short*)(ws + 36 * MB);  // 2MB
  unsigned short* wob  = (unsigned short*)(ws + 38 * MB);  // 2MB
  unsigned short* Gp   = (unsigned short*)(ws + 40 * MB);  // 32MB [4b][4p][1024][1024] (lower tiles)
  unsigned short* G    = (unsigned short*)(ws + 72 * MB);  // 8MB  [4b][1024][1024]  -> peak 80MB
  // reuse dead regions (Gp dead after mirror_reduce):
  float*          Mp   = (float*)        (ws + 40 * MB);   // 8MB  [64 bh][8 es][64][64] f32
  unsigned short* Amat = (unsigned short*)(ws + 48 * MB);  // 8MB  [4b][1024 e][1024 i]
  unsigned short* Weff = (unsigned short*)(ws + 56 * MB);  // 8MB  [4b][1024 j][1024 e]

  const long M1 = 1048576;

  // all converts in one launch
  prep<<<5376, 256, 0, stream>>>(x, wqkv, wo, xb, xT, wqt, wk, wv, wob);

  // G_b = x_b^T x_b : lower triangle, split-K x4 (576 blocks, swizzled, 8 waves, dbuf)
  gemm_tri<<<576, 512, 0, stream>>>(xT, Gp);
  mirror_reduce<<<dim3(36, 4), 256, 0, stream>>>(Gp, G);

  // M partials directly: Mp[bh][es] = (wk_h @ G_b[e-slice]) @ wv_h-slice^T   (512 blocks)
  mdirect<<<512, 512, 0, stream>>>(wk, G, wv, Mp);

  // fused: reduce Mp -> Mt -> Amat_b = Wq^T * blockdiag(SCALE*M_b)   (512 blocks)
  amat_fused<<<dim3(8, 64), 256, 0, stream>>>(Mp, wqt, Amat);

  // Weff_b[j][e] = sum_i wo[j][i] * Amat_b[e][i]   (256 blocks, dbuf)
  gemm_bt<false><<<256, 512, 0, stream>>>(wob, 1024, 0, 0,
                                          Amat, 1024, M1, 0,
                                          (void*)Weff, 1024, M1, 0, 1024, 1, 8, 8);

  // out_b = x_b @ Weff_b^T  (fp32 out; 512 blocks, dbuf)
  gemm_bt<true><<<512, 512, 0, stream>>>(xb, 1024, 2048 * 1024L, 0,
                                         Weff, 1024, M1, 0,
                                         (void*)out, 1024, 2048 * 1024L, 0, 1024, 1, 8, 16);
}